// Round 3
// baseline (3656.489 us; speedup 1.0000x reference)
//
#include <hip/hip_runtime.h>

#define B_ 64
#define R_ 196
#define F_ 2048
#define E_ 512
#define H_ 512
#define A_ 512
#define V_ 12000
#define L_ 24

typedef __attribute__((ext_vector_type(8))) short bf16x8;
typedef __attribute__((ext_vector_type(4))) float f32x4;
typedef unsigned short ush;

__device__ __forceinline__ float fast_tanh(float x) {
    float t = __expf(2.f * x);
    return 1.f - 2.f / (t + 1.f);
}
__device__ __forceinline__ float fast_sig(float x) {
    return 1.f / (1.f + __expf(-x));
}
__device__ __forceinline__ ush f2bf(float x) {
    unsigned int u = __float_as_uint(x);
    return (ush)((u + 0x7fffu + ((u >> 16) & 1u)) >> 16);
}
__device__ __forceinline__ float bf2f(ush b) {
    return __uint_as_float(((unsigned int)b) << 16);
}

#define LROW 40   // LDS row stride (32 k-elems + 8 pad) -> <=2-way bank alias

// ---------------------------------------------------------------------------
// gemm_big: C[m,n] = A[m,:K] @ W[n,:K]^T (+bias). Tile 64M x 256N, BK=32,
// 256 threads (4 waves); wave w owns n-range [64w,64w+64): 4x4 16x16 frags.
// SPLIT=3: (hi,lo) bf16x2 inputs, 3 MFMAs -> near-fp32. SPLIT=1: hi only.
// CMAP: 0 = fp32 C[m*ldc+n]; 1 = bf16 C[m*ldc+n];
//       2 = pred layout C[(m&63)*L*V + (m>>6)*V + n] (fp32).
// M multiple of 64 (grid.y); N masked vs grid.x*256.
// ---------------------------------------------------------------------------
template<int SPLIT, int CMAP>
__global__ __launch_bounds__(256) void gemm_big(
    const ush* __restrict__ Ah, const ush* __restrict__ Al, int lda,
    const ush* __restrict__ Wh, const ush* __restrict__ Wl, int ldw,
    const float* __restrict__ bias, void* __restrict__ Cv,
    int ldc, int N, int K)
{
    __shared__ ush sAh[64 * LROW];
    __shared__ ush sBh[256 * LROW];
    __shared__ ush sAl[64 * LROW];
    __shared__ ush sBl[256 * LROW];

    const int tid = threadIdx.x;
    const int lane = tid & 63, w = tid >> 6;
    const int ntile = blockIdx.x * 256;
    const int mtile = blockIdx.y * 64;
    const int fr = lane & 15, kg = (lane >> 4) * 8;
    const int arow = tid >> 2, aq = (tid & 3) * 8;
    const int brow = ntile + tid;
    const bool bok = brow < N;

    f32x4 acc[4][4];
    #pragma unroll
    for (int mf = 0; mf < 4; ++mf)
        #pragma unroll
        for (int nf = 0; nf < 4; ++nf) acc[mf][nf] = {0.f, 0.f, 0.f, 0.f};

    const uint4 zv = make_uint4(0u, 0u, 0u, 0u);

    for (int kb = 0; kb < K; kb += 32) {
        uint4 a_h = *(const uint4*)(Ah + (size_t)(mtile + arow) * lda + kb + aq);
        uint4 b_h[4], b_l[4];
        uint4 a_l;
        #pragma unroll
        for (int q = 0; q < 4; ++q)
            b_h[q] = bok ? *(const uint4*)(Wh + (size_t)brow * ldw + kb + q * 8) : zv;
        if constexpr (SPLIT == 3) {
            a_l = *(const uint4*)(Al + (size_t)(mtile + arow) * lda + kb + aq);
            #pragma unroll
            for (int q = 0; q < 4; ++q)
                b_l[q] = bok ? *(const uint4*)(Wl + (size_t)brow * ldw + kb + q * 8) : zv;
        }

        __syncthreads();
        *(uint4*)(sAh + arow * LROW + aq) = a_h;
        #pragma unroll
        for (int q = 0; q < 4; ++q)
            *(uint4*)(sBh + tid * LROW + q * 8) = b_h[q];
        if constexpr (SPLIT == 3) {
            *(uint4*)(sAl + arow * LROW + aq) = a_l;
            #pragma unroll
            for (int q = 0; q < 4; ++q)
                *(uint4*)(sBl + tid * LROW + q * 8) = b_l[q];
        }
        __syncthreads();

        bf16x8 bh[4], bl[4];
        #pragma unroll
        for (int nf = 0; nf < 4; ++nf) {
            bh[nf] = *(const bf16x8*)(sBh + (w * 64 + nf * 16 + fr) * LROW + kg);
            if constexpr (SPLIT == 3)
                bl[nf] = *(const bf16x8*)(sBl + (w * 64 + nf * 16 + fr) * LROW + kg);
        }
        #pragma unroll
        for (int mf = 0; mf < 4; ++mf) {
            const bf16x8 ah = *(const bf16x8*)(sAh + (mf * 16 + fr) * LROW + kg);
            if constexpr (SPLIT == 3) {
                const bf16x8 al = *(const bf16x8*)(sAl + (mf * 16 + fr) * LROW + kg);
                #pragma unroll
                for (int nf = 0; nf < 4; ++nf) {
                    acc[mf][nf] = __builtin_amdgcn_mfma_f32_16x16x32_bf16(ah, bh[nf], acc[mf][nf], 0, 0, 0);
                    acc[mf][nf] = __builtin_amdgcn_mfma_f32_16x16x32_bf16(ah, bl[nf], acc[mf][nf], 0, 0, 0);
                    acc[mf][nf] = __builtin_amdgcn_mfma_f32_16x16x32_bf16(al, bh[nf], acc[mf][nf], 0, 0, 0);
                }
            } else {
                #pragma unroll
                for (int nf = 0; nf < 4; ++nf)
                    acc[mf][nf] = __builtin_amdgcn_mfma_f32_16x16x32_bf16(ah, bh[nf], acc[mf][nf], 0, 0, 0);
            }
        }
    }

    const int mrow0 = (lane >> 4) * 4;
    #pragma unroll
    for (int nf = 0; nf < 4; ++nf) {
        const int n = ntile + w * 64 + nf * 16 + fr;
        if (n < N) {
            const float bv = bias ? bias[n] : 0.f;
            #pragma unroll
            for (int mf = 0; mf < 4; ++mf) {
                #pragma unroll
                for (int r = 0; r < 4; ++r) {
                    const int m = mtile + mf * 16 + mrow0 + r;
                    const float v = acc[mf][nf][r] + bv;
                    if constexpr (CMAP == 1)
                        ((ush*)Cv)[(size_t)m * ldc + n] = f2bf(v);
                    else if constexpr (CMAP == 2)
                        ((float*)Cv)[(size_t)(m & 63) * (L_ * V_) + (size_t)(m >> 6) * V_ + n] = v;
                    else
                        ((float*)Cv)[(size_t)m * ldc + n] = v;
                }
            }
        }
    }
}

// ---------------------------------------------------------------------------
// gemm_mfma: 64x64 tile, segmented A (2 used), split-K via grid.z (partials).
// Used for the per-step gates GEMM: [ctx | h] @ [W_ih[:,E:] | W_hh]^T.
// ---------------------------------------------------------------------------
__global__ __launch_bounds__(256) void gemm_gates(
    const ush* __restrict__ Ah0, const ush* __restrict__ Al0, int lda0, int k0,
    const ush* __restrict__ Ah1, const ush* __restrict__ Al1, int lda1,
    const ush* __restrict__ Wh, const ush* __restrict__ Wl, int ldw,
    float* __restrict__ C, int ldc, long zstride, int kChunk)
{
    __shared__ ush sAh[64 * LROW];
    __shared__ ush sBh[64 * LROW];
    __shared__ ush sAl[64 * LROW];
    __shared__ ush sBl[64 * LROW];

    const int tid = threadIdx.x;
    const int ntile = blockIdx.x * 64;
    const int kStart = blockIdx.z * kChunk;
    const int lane = tid & 63, w = tid >> 6;
    const int lrow = tid >> 2;
    const int lcol = (tid & 3) * 8;
    const int nrow = ntile + lrow;

    f32x4 acc[4];
    #pragma unroll
    for (int f = 0; f < 4; ++f) acc[f] = {0.f, 0.f, 0.f, 0.f};

    const int fr = lane & 15;
    const int kg = (lane >> 4) * 8;

    for (int kb = kStart; kb < kStart + kChunk; kb += 32) {
        const ush *ph, *pl; int lda, loc;
        if (kb < k0) { ph = Ah0; pl = Al0; lda = lda0; loc = kb; }
        else         { ph = Ah1; pl = Al1; lda = lda1; loc = kb - k0; }

        uint4 a_h = *(const uint4*)(ph + (size_t)lrow * lda + loc + lcol);
        uint4 b_h = *(const uint4*)(Wh + (size_t)nrow * ldw + kb + lcol);
        uint4 a_l = *(const uint4*)(pl + (size_t)lrow * lda + loc + lcol);
        uint4 b_l = *(const uint4*)(Wl + (size_t)nrow * ldw + kb + lcol);

        __syncthreads();
        *(uint4*)(sAh + lrow * LROW + lcol) = a_h;
        *(uint4*)(sBh + lrow * LROW + lcol) = b_h;
        *(uint4*)(sAl + lrow * LROW + lcol) = a_l;
        *(uint4*)(sBl + lrow * LROW + lcol) = b_l;
        __syncthreads();

        const bf16x8 bh = *(const bf16x8*)(sBh + (16 * w + fr) * LROW + kg);
        const bf16x8 bl = *(const bf16x8*)(sBl + (16 * w + fr) * LROW + kg);

        #pragma unroll
        for (int f = 0; f < 4; ++f) {
            const bf16x8 ah = *(const bf16x8*)(sAh + (16 * f + fr) * LROW + kg);
            const bf16x8 al = *(const bf16x8*)(sAl + (16 * f + fr) * LROW + kg);
            acc[f] = __builtin_amdgcn_mfma_f32_16x16x32_bf16(ah, bh, acc[f], 0, 0, 0);
            acc[f] = __builtin_amdgcn_mfma_f32_16x16x32_bf16(ah, bl, acc[f], 0, 0, 0);
            acc[f] = __builtin_amdgcn_mfma_f32_16x16x32_bf16(al, bh, acc[f], 0, 0, 0);
        }
    }

    const int n = ntile + 16 * w + (lane & 15);
    float* Cz = C + (size_t)blockIdx.z * zstride;
    #pragma unroll
    for (int f = 0; f < 4; ++f)
        #pragma unroll
        for (int r = 0; r < 4; ++r) {
            const int m = 16 * f + (lane >> 4) * 4 + r;
            Cz[(size_t)m * ldc + n] = acc[f][r];
        }
}

// mean over regions -> bf16 hi/lo
__global__ __launch_bounds__(256) void mean_split(
    const float* __restrict__ feats, ush* __restrict__ mh, ush* __restrict__ ml)
{
    const int idx = blockIdx.x * 256 + threadIdx.x;   // 32768
    const int b = idx >> 9, j = idx & 511;
    const float4* fp = reinterpret_cast<const float4*>(feats) + (size_t)b * R_ * (F_ / 4) + j;
    float4 acc = make_float4(0.f, 0.f, 0.f, 0.f);
    for (int r = 0; r < R_; ++r) {
        const float4 v = fp[(size_t)r * (F_ / 4)];
        acc.x += v.x; acc.y += v.y; acc.z += v.z; acc.w += v.w;
    }
    const float s = 1.f / (float)R_;
    const float a[4] = {acc.x * s, acc.y * s, acc.z * s, acc.w * s};
    #pragma unroll
    for (int c = 0; c < 4; ++c) {
        const ush hi = f2bf(a[c]);
        mh[idx * 4 + c] = hi;
        ml[idx * 4 + c] = f2bf(a[c] - bf2f(hi));
    }
}

// gather embeddings -> bf16 hi/lo (B,L,E)
__global__ __launch_bounds__(256) void gather_split(
    const float* __restrict__ emb, const int* __restrict__ cap,
    ush* __restrict__ eh, ush* __restrict__ el)
{
    const int idx = blockIdx.x * 256 + threadIdx.x;   // 196608
    const int bt = idx >> 7, j = idx & 127;
    const int tok = cap[bt];
    const float4 v = reinterpret_cast<const float4*>(emb)[(size_t)tok * (E_ / 4) + j];
    const float a[4] = {v.x, v.y, v.z, v.w};
    #pragma unroll
    for (int c = 0; c < 4; ++c) {
        const ush hi = f2bf(a[c]);
        eh[idx * 4 + c] = hi;
        el[idx * 4 + c] = f2bf(a[c] - bf2f(hi));
    }
}

// generic fp32 -> bf16 (hi, optional lo)
__global__ __launch_bounds__(256) void split_kernel(
    const float* __restrict__ in, ush* __restrict__ hi, ush* __restrict__ lo, int n4)
{
    for (int i = blockIdx.x * 256 + threadIdx.x; i < n4; i += gridDim.x * 256) {
        const float4 v = reinterpret_cast<const float4*>(in)[i];
        const float a[4] = {v.x, v.y, v.z, v.w};
        #pragma unroll
        for (int c = 0; c < 4; ++c) {
            const ush h = f2bf(a[c]);
            hi[i * 4 + c] = h;
            if (lo) lo[i * 4 + c] = f2bf(a[c] - bf2f(h));
        }
    }
}

// W_ih columns [0:E) -> wx (2048x512); [E:) ++ W_hh -> wg2 (2048x2560); hi/lo
__global__ __launch_bounds__(256) void prep_wih(
    const float* __restrict__ W_ih, const float* __restrict__ W_hh,
    ush* __restrict__ wxh, ush* __restrict__ wxl,
    ush* __restrict__ wg2h, ush* __restrict__ wg2l)
{
    const int nrow = blockIdx.x;   // 2048
    for (int k = threadIdx.x; k < E_; k += 256) {
        const float v = W_ih[(size_t)nrow * (E_ + F_) + k];
        const ush h = f2bf(v);
        wxh[(size_t)nrow * E_ + k] = h;
        wxl[(size_t)nrow * E_ + k] = f2bf(v - bf2f(h));
    }
    for (int k = threadIdx.x; k < F_ + H_; k += 256) {
        const float v = (k < F_) ? W_ih[(size_t)nrow * (E_ + F_) + E_ + k]
                                 : W_hh[(size_t)nrow * H_ + (k - F_)];
        const ush h = f2bf(v);
        wg2h[(size_t)nrow * (F_ + H_) + k] = h;
        wg2l[(size_t)nrow * (F_ + H_) + k] = f2bf(v - bf2f(h));
    }
}

// attention scores + softmax: one block per batch element
__global__ __launch_bounds__(256) void attn_score(
    const float* __restrict__ h, const float* __restrict__ W_hidp,
    const float* __restrict__ b_hidp, const ush* __restrict__ fpb,
    const float* __restrict__ W_score, const float* __restrict__ b_score,
    float* __restrict__ alpha, float* __restrict__ alph_out, int t)
{
    __shared__ float sh_h[H_];
    __shared__ float sh_hp[A_];
    __shared__ float sh_ws[A_];
    __shared__ float sh_sc[200];
    __shared__ float red[2];
    const int tid = threadIdx.x;
    const int b = blockIdx.x;

    sh_h[tid] = h[b * H_ + tid];
    sh_h[tid + 256] = h[b * H_ + 256 + tid];
    sh_ws[tid] = W_score[tid];
    sh_ws[tid + 256] = W_score[tid + 256];
    __syncthreads();

    for (int a = tid; a < A_; a += 256) {
        const float4* wr = reinterpret_cast<const float4*>(W_hidp + (size_t)a * H_);
        float acc = 0.f;
        #pragma unroll 8
        for (int kk = 0; kk < H_ / 4; ++kk) {
            const float4 w4 = wr[kk];
            acc += w4.x * sh_h[kk * 4 + 0] + w4.y * sh_h[kk * 4 + 1]
                 + w4.z * sh_h[kk * 4 + 2] + w4.w * sh_h[kk * 4 + 3];
        }
        sh_hp[a] = acc + b_hidp[a];
    }
    __syncthreads();

    const int lane = tid & 63, wid = tid >> 6;
    for (int r = wid; r < R_; r += 4) {
        const ushort2* row = reinterpret_cast<const ushort2*>(fpb + ((size_t)b * R_ + r) * A_);
        float acc = 0.f;
        #pragma unroll
        for (int j = 0; j < 4; ++j) {
            const ushort2 u = row[lane + 64 * j];
            const int a = 2 * (lane + 64 * j);
            acc += fast_tanh(bf2f(u.x) + sh_hp[a]) * sh_ws[a];
            acc += fast_tanh(bf2f(u.y) + sh_hp[a + 1]) * sh_ws[a + 1];
        }
        for (int off = 32; off > 0; off >>= 1) acc += __shfl_down(acc, off);
        if (lane == 0) sh_sc[r] = acc + b_score[0];
    }
    __syncthreads();

    if (tid < 64) {
        float m = -1e30f;
        for (int r = tid; r < R_; r += 64) m = fmaxf(m, sh_sc[r]);
        for (int off = 32; off > 0; off >>= 1) m = fmaxf(m, __shfl_xor(m, off));
        float s = 0.f;
        for (int r = tid; r < R_; r += 64) s += __expf(sh_sc[r] - m);
        for (int off = 32; off > 0; off >>= 1) s += __shfl_xor(s, off);
        if (tid == 0) { red[0] = m; red[1] = 1.f / s; }
    }
    __syncthreads();
    const float m = red[0], is = red[1];
    if (tid < R_) {
        const float av = __expf(sh_sc[tid] - m) * is;
        alpha[b * R_ + tid] = av;
        alph_out[((size_t)b * L_ + t) * R_ + tid] = av;
    }
}

// context quarter: ctx[b, rs*512 + 2*tid + {0,1}] from fp32 feats
__global__ __launch_bounds__(256) void attn_context(
    const float* __restrict__ feats, const float* __restrict__ alpha,
    ush* __restrict__ ctx_hi, ush* __restrict__ ctx_lo)
{
    __shared__ float sa[R_];
    const int tid = threadIdx.x;
    const int rs = blockIdx.x;
    const int b = blockIdx.y;
    if (tid < R_) sa[tid] = alpha[b * R_ + tid];
    __syncthreads();

    const int f0 = rs * 512 + tid * 2;
    const float2* fp = reinterpret_cast<const float2*>(feats + (size_t)b * R_ * F_ + f0);
    float cx = 0.f, cy = 0.f;
    #pragma unroll 4
    for (int r = 0; r < R_; ++r) {
        const float a = sa[r];
        const float2 v = fp[(size_t)r * (F_ / 2)];
        cx = fmaf(a, v.x, cx); cy = fmaf(a, v.y, cy);
    }
    const size_t ci = (size_t)b * F_ + f0;
    const ush hx = f2bf(cx);
    ctx_hi[ci] = hx; ctx_lo[ci] = f2bf(cx - bf2f(hx));
    const ush hy = f2bf(cy);
    ctx_hi[ci + 1] = hy; ctx_lo[ci + 1] = f2bf(cy - bf2f(hy));
}

// LSTM cell: reduce 8 split-K partials + egates + biases; update h,c;
// write bf16 h into current (h_hi/h_lo) and history (hall) buffers
__global__ __launch_bounds__(256) void cell_kernel(
    const float* __restrict__ gparts, const float* __restrict__ egates,
    const float* __restrict__ b_ih, const float* __restrict__ b_hh,
    float* __restrict__ h, float* __restrict__ c,
    ush* __restrict__ h_hi, ush* __restrict__ h_lo,
    ush* __restrict__ hall_hi, ush* __restrict__ hall_lo, int t)
{
    const int idx = blockIdx.x * 256 + threadIdx.x;   // B*H = 32768
    const int b = idx >> 9, n = idx & 511;
    const float* eg = egates + ((size_t)b * L_ + t) * 2048;
    float gi = b_ih[n] + b_hh[n] + eg[n];
    float gf = b_ih[n + 512] + b_hh[n + 512] + eg[n + 512];
    float gg = b_ih[n + 1024] + b_hh[n + 1024] + eg[n + 1024];
    float go = b_ih[n + 1536] + b_hh[n + 1536] + eg[n + 1536];
    #pragma unroll
    for (int z = 0; z < 8; ++z) {
        const float* gz = gparts + (size_t)z * B_ * 2048 + (size_t)b * 2048;
        gi += gz[n]; gf += gz[n + 512]; gg += gz[n + 1024]; go += gz[n + 1536];
    }
    const float cc = fast_sig(gf) * c[idx] + fast_sig(gi) * fast_tanh(gg);
    const float hh = fast_sig(go) * fast_tanh(cc);
    c[idx] = cc;
    h[idx] = hh;
    const ush hi = f2bf(hh);
    const ush lo = f2bf(hh - bf2f(hi));
    h_hi[idx] = hi;
    h_lo[idx] = lo;
    const size_t hidx = ((size_t)t * B_ + b) * H_ + n;
    hall_hi[hidx] = hi;
    hall_lo[hidx] = lo;
}

extern "C" void kernel_launch(void* const* d_in, const int* in_sizes, int n_in,
                              void* d_out, int out_size, void* d_ws, size_t ws_size,
                              hipStream_t stream)
{
    const float* feats    = (const float*)d_in[0];
    const int*   cap      = (const int*)  d_in[1];
    const float* emb      = (const float*)d_in[2];
    const float* W_init_h = (const float*)d_in[3];
    const float* b_init_h = (const float*)d_in[4];
    const float* W_init_c = (const float*)d_in[5];
    const float* b_init_c = (const float*)d_in[6];
    const float* W_ih     = (const float*)d_in[7];
    const float* b_ih     = (const float*)d_in[8];
    const float* W_hh     = (const float*)d_in[9];
    const float* b_hh     = (const float*)d_in[10];
    const float* W_featp  = (const float*)d_in[11];
    const float* b_featp  = (const float*)d_in[12];
    const float* W_hidp   = (const float*)d_in[13];
    const float* b_hidp   = (const float*)d_in[14];
    const float* W_score  = (const float*)d_in[15];
    const float* b_score  = (const float*)d_in[16];
    const float* W_out    = (const float*)d_in[17];
    const float* b_out    = (const float*)d_in[18];

    float* pred     = (float*)d_out;                          // (B,L,V)
    float* alph_out = pred + (size_t)B_ * L_ * V_;            // (B,L,R)

    char* p = (char*)d_ws;
    auto alloc = [&](size_t bytes) { char* q = p; p += (bytes + 255) & ~(size_t)255; return q; };

    ush*   fpb    = (ush*)  alloc((size_t)B_ * R_ * A_ * 2);
    ush*   eh     = (ush*)  alloc((size_t)B_ * L_ * E_ * 2);
    ush*   el     = (ush*)  alloc((size_t)B_ * L_ * E_ * 2);
    ush*   mh     = (ush*)  alloc((size_t)B_ * F_ * 2);
    ush*   ml     = (ush*)  alloc((size_t)B_ * F_ * 2);
    ush*   fbh    = (ush*)  alloc((size_t)B_ * R_ * F_ * 2);
    ush*   wfp_h  = (ush*)  alloc((size_t)A_ * F_ * 2);
    ush*   wihh   = (ush*)  alloc((size_t)H_ * F_ * 2);
    ush*   wihl   = (ush*)  alloc((size_t)H_ * F_ * 2);
    ush*   wich   = (ush*)  alloc((size_t)H_ * F_ * 2);
    ush*   wicl   = (ush*)  alloc((size_t)H_ * F_ * 2);
    ush*   wxh    = (ush*)  alloc((size_t)2048 * E_ * 2);
    ush*   wxl    = (ush*)  alloc((size_t)2048 * E_ * 2);
    ush*   wg2h   = (ush*)  alloc((size_t)2048 * (F_ + H_) * 2);
    ush*   wg2l   = (ush*)  alloc((size_t)2048 * (F_ + H_) * 2);
    ush*   woh    = (ush*)  alloc((size_t)V_ * H_ * 2);
    ush*   wol    = (ush*)  alloc((size_t)V_ * H_ * 2);
    float* egates = (float*)alloc((size_t)B_ * L_ * 2048 * 4);
    float* h      = (float*)alloc((size_t)B_ * H_ * 4);
    float* c      = (float*)alloc((size_t)B_ * H_ * 4);
    ush*   h_hi   = (ush*)  alloc((size_t)B_ * H_ * 2);
    ush*   h_lo   = (ush*)  alloc((size_t)B_ * H_ * 2);
    ush*   hallh  = (ush*)  alloc((size_t)L_ * B_ * H_ * 2);
    ush*   halll  = (ush*)  alloc((size_t)L_ * B_ * H_ * 2);
    ush*   ctx_hi = (ush*)  alloc((size_t)B_ * F_ * 2);
    ush*   ctx_lo = (ush*)  alloc((size_t)B_ * F_ * 2);
    float* alpha  = (float*)alloc((size_t)B_ * R_ * 4);
    float* gparts = (float*)alloc((size_t)8 * B_ * 2048 * 4);

    // ---- one-time prep ----
    mean_split<<<128, 256, 0, stream>>>(feats, mh, ml);
    gather_split<<<768, 256, 0, stream>>>(emb, cap, eh, el);
    split_kernel<<<2048, 256, 0, stream>>>(W_out, woh, wol, V_ * H_ / 4);
    split_kernel<<<512, 256, 0, stream>>>(W_init_h, wihh, wihl, H_ * F_ / 4);
    split_kernel<<<512, 256, 0, stream>>>(W_init_c, wich, wicl, H_ * F_ / 4);
    split_kernel<<<512, 256, 0, stream>>>(W_featp, wfp_h, nullptr, A_ * F_ / 4);
    split_kernel<<<2048, 256, 0, stream>>>(feats, fbh, nullptr, B_ * R_ * F_ / 4);
    prep_wih<<<2048, 256, 0, stream>>>(W_ih, W_hh, wxh, wxl, wg2h, wg2l);

    // h0/c0 (SPLIT=3): M=64, N=512, K=2048
    gemm_big<3, 0><<<dim3(2, 1), 256, 0, stream>>>(
        mh, ml, F_, wihh, wihl, F_, b_init_h, h, H_, H_, F_);
    gemm_big<3, 0><<<dim3(2, 1), 256, 0, stream>>>(
        mh, ml, F_, wich, wicl, F_, b_init_c, c, H_, H_, F_);
    split_kernel<<<32, 256, 0, stream>>>(h, h_hi, h_lo, B_ * H_ / 4);

    // feat_proj (SPLIT=1, bf16 out): M=12544, N=512, K=2048
    gemm_big<1, 1><<<dim3(2, 196), 256, 0, stream>>>(
        fbh, nullptr, F_, wfp_h, nullptr, F_, b_featp, fpb, A_, A_, F_);

    // emb gate part for ALL steps (SPLIT=3): M=B*L=1536, N=2048, K=512
    gemm_big<3, 0><<<dim3(8, 24), 256, 0, stream>>>(
        eh, el, E_, wxh, wxl, E_, nullptr, egates, 2048, 2048, E_);

    // ---- sequential decode ----
    for (int t = 0; t < L_; ++t) {
        attn_score<<<B_, 256, 0, stream>>>(
            h, W_hidp, b_hidp, fpb, W_score, b_score, alpha, alph_out, t);

        attn_context<<<dim3(4, B_), 256, 0, stream>>>(feats, alpha, ctx_hi, ctx_lo);

        // gates partials: [ctx | h] @ wg2^T, K=2560, split-K=8 (kChunk=320)
        gemm_gates<<<dim3(32, 1, 8), 256, 0, stream>>>(
            ctx_hi, ctx_lo, F_, F_,
            h_hi, h_lo, H_,
            wg2h, wg2l, F_ + H_,
            gparts, 4 * H_, (long)B_ * 4 * H_, (F_ + H_) / 8);

        cell_kernel<<<128, 256, 0, stream>>>(
            gparts, egates, b_ih, b_hh, h, c, h_hi, h_lo, hallh, halll, t);
    }

    // predictions for ALL steps (SPLIT=3): M=L*B=1536, N=12000, K=512
    gemm_big<3, 2><<<dim3(47, 24), 256, 0, stream>>>(
        hallh, halll, H_, woh, wol, H_, b_out, pred, 0, V_, H_);
}

// Round 4
// 3038.890 us; speedup vs baseline: 1.2032x; 1.2032x over previous
//
#include <hip/hip_runtime.h>

#define B_ 64
#define R_ 196
#define F_ 2048
#define E_ 512
#define H_ 512
#define A_ 512
#define V_ 12000
#define L_ 24

typedef __attribute__((ext_vector_type(8))) short bf16x8;
typedef __attribute__((ext_vector_type(4))) float f32x4;
typedef unsigned short ush;

__device__ __forceinline__ float fast_tanh(float x) {
    float t = __expf(2.f * x);
    return 1.f - 2.f / (t + 1.f);
}
__device__ __forceinline__ float fast_sig(float x) {
    return 1.f / (1.f + __expf(-x));
}
__device__ __forceinline__ ush f2bf(float x) {
    unsigned int u = __float_as_uint(x);
    return (ush)((u + 0x7fffu + ((u >> 16) & 1u)) >> 16);
}
__device__ __forceinline__ float bf2f(ush b) {
    return __uint_as_float(((unsigned int)b) << 16);
}

#define LROW 40   // LDS row stride (32 k-elems + 8 pad)

// ---------------------------------------------------------------------------
// gemm_big: C[m,n] = A[m,:K] @ W[n,:K]^T (+bias). Tile 64M x 256N, BK=32,
// 256 threads (4 waves); wave w owns n-range [64w,64w+64): 4x4 16x16 frags.
// grid = (x = m-tile, y = n-tile)  -> consecutive blocks SHARE the B n-tile
// (L2 reuse; B is the big operand in the pred GEMM).
// SPLIT=3: (hi,lo) bf16x2 inputs, 3 MFMAs -> near-fp32. SPLIT=1: hi only.
// CMAP: 0 = fp32 C[m*ldc+n]; 1 = bf16 C[m*ldc+n];
//       2 = pred layout C[(m&63)*L*V + (m>>6)*V + n] (fp32).
// Epilogue stages 16-row quarters through LDS -> full-line coalesced stores.
// M multiple of 64 (grid.x); N masked vs grid.y*256.
// ---------------------------------------------------------------------------
template<int SPLIT, int CMAP>
__global__ __launch_bounds__(256) void gemm_big(
    const ush* __restrict__ Ah, const ush* __restrict__ Al, int lda,
    const ush* __restrict__ Wh, const ush* __restrict__ Wl, int ldw,
    const float* __restrict__ bias, void* __restrict__ Cv,
    int ldc, int N, int K)
{
    constexpr int SMEM_BYTES = (SPLIT == 3) ? 51200 : 25600;
    __shared__ __align__(16) char smem[SMEM_BYTES];
    ush* sAh = (ush*)smem;                    // 64  x LROW
    ush* sBh = (ush*)(smem + 5120);           // 256 x LROW
    ush* sAl = (ush*)(smem + 25600);
    ush* sBl = (ush*)(smem + 30720);
    float* cst = (float*)(smem + 5120);       // epilogue reuse (16KB <= 20KB)

    const int tid = threadIdx.x;
    const int lane = tid & 63, w = tid >> 6;
    const int mtile = blockIdx.x * 64;
    const int ntile = blockIdx.y * 256;
    const int fr = lane & 15, kg = (lane >> 4) * 8;
    const int arow = tid >> 2, aq = (tid & 3) * 8;   // staging coords

    f32x4 acc[4][4];
    #pragma unroll
    for (int mf = 0; mf < 4; ++mf)
        #pragma unroll
        for (int nf = 0; nf < 4; ++nf) acc[mf][nf] = {0.f, 0.f, 0.f, 0.f};

    const uint4 zv = make_uint4(0u, 0u, 0u, 0u);

    for (int kb = 0; kb < K; kb += 32) {
        uint4 a_h = *(const uint4*)(Ah + (size_t)(mtile + arow) * lda + kb + aq);
        uint4 a_l;
        uint4 b_h[4], b_l[4];
        #pragma unroll
        for (int p = 0; p < 4; ++p) {
            const int row = ntile + arow + 64 * p;
            b_h[p] = (row < N) ? *(const uint4*)(Wh + (size_t)row * ldw + kb + aq) : zv;
        }
        if constexpr (SPLIT == 3) {
            a_l = *(const uint4*)(Al + (size_t)(mtile + arow) * lda + kb + aq);
            #pragma unroll
            for (int p = 0; p < 4; ++p) {
                const int row = ntile + arow + 64 * p;
                b_l[p] = (row < N) ? *(const uint4*)(Wl + (size_t)row * ldw + kb + aq) : zv;
            }
        }

        __syncthreads();
        *(uint4*)(sAh + arow * LROW + aq) = a_h;
        #pragma unroll
        for (int p = 0; p < 4; ++p)
            *(uint4*)(sBh + (arow + 64 * p) * LROW + aq) = b_h[p];
        if constexpr (SPLIT == 3) {
            *(uint4*)(sAl + arow * LROW + aq) = a_l;
            #pragma unroll
            for (int p = 0; p < 4; ++p)
                *(uint4*)(sBl + (arow + 64 * p) * LROW + aq) = b_l[p];
        }
        __syncthreads();

        bf16x8 bh[4], bl[4];
        #pragma unroll
        for (int nf = 0; nf < 4; ++nf) {
            bh[nf] = *(const bf16x8*)(sBh + (w * 64 + nf * 16 + fr) * LROW + kg);
            if constexpr (SPLIT == 3)
                bl[nf] = *(const bf16x8*)(sBl + (w * 64 + nf * 16 + fr) * LROW + kg);
        }
        #pragma unroll
        for (int mf = 0; mf < 4; ++mf) {
            const bf16x8 ah = *(const bf16x8*)(sAh + (mf * 16 + fr) * LROW + kg);
            if constexpr (SPLIT == 3) {
                const bf16x8 al = *(const bf16x8*)(sAl + (mf * 16 + fr) * LROW + kg);
                #pragma unroll
                for (int nf = 0; nf < 4; ++nf) {
                    acc[mf][nf] = __builtin_amdgcn_mfma_f32_16x16x32_bf16(ah, bh[nf], acc[mf][nf], 0, 0, 0);
                    acc[mf][nf] = __builtin_amdgcn_mfma_f32_16x16x32_bf16(ah, bl[nf], acc[mf][nf], 0, 0, 0);
                    acc[mf][nf] = __builtin_amdgcn_mfma_f32_16x16x32_bf16(al, bh[nf], acc[mf][nf], 0, 0, 0);
                }
            } else {
                #pragma unroll
                for (int nf = 0; nf < 4; ++nf)
                    acc[mf][nf] = __builtin_amdgcn_mfma_f32_16x16x32_bf16(ah, bh[nf], acc[mf][nf], 0, 0, 0);
            }
        }
    }

    // ---- LDS-staged epilogue: 4 quarters of 16 rows, full-line stores ----
    __syncthreads();
    const int nstore = ntile + tid;
    const bool sok = nstore < N;
    const float bv = (sok && bias) ? bias[nstore] : 0.f;
    const int colw = w * 64;
    #pragma unroll
    for (int mf = 0; mf < 4; ++mf) {
        #pragma unroll
        for (int nf = 0; nf < 4; ++nf) {
            const int col = colw + nf * 16 + fr;
            #pragma unroll
            for (int r = 0; r < 4; ++r)
                cst[((lane >> 4) * 4 + r) * 256 + col] = acc[mf][nf][r];
        }
        __syncthreads();
        if (sok) {
            #pragma unroll
            for (int rowq = 0; rowq < 16; ++rowq) {
                const int m = mtile + mf * 16 + rowq;
                const float v = cst[rowq * 256 + tid] + bv;
                if constexpr (CMAP == 1)
                    ((ush*)Cv)[(size_t)m * ldc + nstore] = f2bf(v);
                else if constexpr (CMAP == 2)
                    ((float*)Cv)[(size_t)(m & 63) * (L_ * V_) + (size_t)(m >> 6) * V_ + nstore] = v;
                else
                    ((float*)Cv)[(size_t)m * ldc + nstore] = v;
            }
        }
        __syncthreads();
    }
}

// ---------------------------------------------------------------------------
// gemm_gates: 64x64 tile, segmented A (2 segments), split-K via grid.z.
// Per-step gates GEMM: [ctx | h] @ [W_ih[:,E:] | W_hh]^T -> partials.
// ---------------------------------------------------------------------------
__global__ __launch_bounds__(256) void gemm_gates(
    const ush* __restrict__ Ah0, const ush* __restrict__ Al0, int lda0, int k0,
    const ush* __restrict__ Ah1, const ush* __restrict__ Al1, int lda1,
    const ush* __restrict__ Wh, const ush* __restrict__ Wl, int ldw,
    float* __restrict__ C, int ldc, long zstride, int kChunk)
{
    __shared__ ush sAh[64 * LROW];
    __shared__ ush sBh[64 * LROW];
    __shared__ ush sAl[64 * LROW];
    __shared__ ush sBl[64 * LROW];

    const int tid = threadIdx.x;
    const int ntile = blockIdx.x * 64;
    const int kStart = blockIdx.z * kChunk;
    const int lane = tid & 63, w = tid >> 6;
    const int lrow = tid >> 2;
    const int lcol = (tid & 3) * 8;
    const int nrow = ntile + lrow;

    f32x4 acc[4];
    #pragma unroll
    for (int f = 0; f < 4; ++f) acc[f] = {0.f, 0.f, 0.f, 0.f};

    const int fr = lane & 15;
    const int kg = (lane >> 4) * 8;

    for (int kb = kStart; kb < kStart + kChunk; kb += 32) {
        const ush *ph, *pl; int lda, loc;
        if (kb < k0) { ph = Ah0; pl = Al0; lda = lda0; loc = kb; }
        else         { ph = Ah1; pl = Al1; lda = lda1; loc = kb - k0; }

        uint4 a_h = *(const uint4*)(ph + (size_t)lrow * lda + loc + lcol);
        uint4 b_h = *(const uint4*)(Wh + (size_t)nrow * ldw + kb + lcol);
        uint4 a_l = *(const uint4*)(pl + (size_t)lrow * lda + loc + lcol);
        uint4 b_l = *(const uint4*)(Wl + (size_t)nrow * ldw + kb + lcol);

        __syncthreads();
        *(uint4*)(sAh + lrow * LROW + lcol) = a_h;
        *(uint4*)(sBh + lrow * LROW + lcol) = b_h;
        *(uint4*)(sAl + lrow * LROW + lcol) = a_l;
        *(uint4*)(sBl + lrow * LROW + lcol) = b_l;
        __syncthreads();

        const bf16x8 bh = *(const bf16x8*)(sBh + (16 * w + fr) * LROW + kg);
        const bf16x8 bl = *(const bf16x8*)(sBl + (16 * w + fr) * LROW + kg);

        #pragma unroll
        for (int f = 0; f < 4; ++f) {
            const bf16x8 ah = *(const bf16x8*)(sAh + (16 * f + fr) * LROW + kg);
            const bf16x8 al = *(const bf16x8*)(sAl + (16 * f + fr) * LROW + kg);
            acc[f] = __builtin_amdgcn_mfma_f32_16x16x32_bf16(ah, bh, acc[f], 0, 0, 0);
            acc[f] = __builtin_amdgcn_mfma_f32_16x16x32_bf16(ah, bl, acc[f], 0, 0, 0);
            acc[f] = __builtin_amdgcn_mfma_f32_16x16x32_bf16(al, bh, acc[f], 0, 0, 0);
        }
    }

    const int n = ntile + 16 * w + (lane & 15);
    float* Cz = C + (size_t)blockIdx.z * zstride;
    #pragma unroll
    for (int f = 0; f < 4; ++f)
        #pragma unroll
        for (int r = 0; r < 4; ++r) {
            const int m = 16 * f + (lane >> 4) * 4 + r;
            Cz[(size_t)m * ldc + n] = acc[f][r];
        }
}

// mean over regions -> bf16 hi/lo
__global__ __launch_bounds__(256) void mean_split(
    const float* __restrict__ feats, ush* __restrict__ mh, ush* __restrict__ ml)
{
    const int idx = blockIdx.x * 256 + threadIdx.x;   // 32768
    const int b = idx >> 9, j = idx & 511;
    const float4* fp = reinterpret_cast<const float4*>(feats) + (size_t)b * R_ * (F_ / 4) + j;
    float4 acc = make_float4(0.f, 0.f, 0.f, 0.f);
    for (int r = 0; r < R_; ++r) {
        const float4 v = fp[(size_t)r * (F_ / 4)];
        acc.x += v.x; acc.y += v.y; acc.z += v.z; acc.w += v.w;
    }
    const float s = 1.f / (float)R_;
    const float a[4] = {acc.x * s, acc.y * s, acc.z * s, acc.w * s};
    #pragma unroll
    for (int c = 0; c < 4; ++c) {
        const ush hi = f2bf(a[c]);
        mh[idx * 4 + c] = hi;
        ml[idx * 4 + c] = f2bf(a[c] - bf2f(hi));
    }
}

// gather embeddings -> bf16 hi/lo (B,L,E)
__global__ __launch_bounds__(256) void gather_split(
    const float* __restrict__ emb, const int* __restrict__ cap,
    ush* __restrict__ eh, ush* __restrict__ el)
{
    const int idx = blockIdx.x * 256 + threadIdx.x;   // 196608
    const int bt = idx >> 7, j = idx & 127;
    const int tok = cap[bt];
    const float4 v = reinterpret_cast<const float4*>(emb)[(size_t)tok * (E_ / 4) + j];
    const float a[4] = {v.x, v.y, v.z, v.w};
    #pragma unroll
    for (int c = 0; c < 4; ++c) {
        const ush hi = f2bf(a[c]);
        eh[idx * 4 + c] = hi;
        el[idx * 4 + c] = f2bf(a[c] - bf2f(hi));
    }
}

// generic fp32 -> bf16 (hi, optional lo)
__global__ __launch_bounds__(256) void split_kernel(
    const float* __restrict__ in, ush* __restrict__ hi, ush* __restrict__ lo, int n4)
{
    for (int i = blockIdx.x * 256 + threadIdx.x; i < n4; i += gridDim.x * 256) {
        const float4 v = reinterpret_cast<const float4*>(in)[i];
        const float a[4] = {v.x, v.y, v.z, v.w};
        #pragma unroll
        for (int c = 0; c < 4; ++c) {
            const ush h = f2bf(a[c]);
            hi[i * 4 + c] = h;
            if (lo) lo[i * 4 + c] = f2bf(a[c] - bf2f(h));
        }
    }
}

// W_ih columns [0:E) -> wx (2048x512); [E:) ++ W_hh -> wg2 (2048x2560); hi/lo
__global__ __launch_bounds__(256) void prep_wih(
    const float* __restrict__ W_ih, const float* __restrict__ W_hh,
    ush* __restrict__ wxh, ush* __restrict__ wxl,
    ush* __restrict__ wg2h, ush* __restrict__ wg2l)
{
    const int nrow = blockIdx.x;   // 2048
    for (int k = threadIdx.x; k < E_; k += 256) {
        const float v = W_ih[(size_t)nrow * (E_ + F_) + k];
        const ush h = f2bf(v);
        wxh[(size_t)nrow * E_ + k] = h;
        wxl[(size_t)nrow * E_ + k] = f2bf(v - bf2f(h));
    }
    for (int k = threadIdx.x; k < F_ + H_; k += 256) {
        const float v = (k < F_) ? W_ih[(size_t)nrow * (E_ + F_) + E_ + k]
                                 : W_hh[(size_t)nrow * H_ + (k - F_)];
        const ush h = f2bf(v);
        wg2h[(size_t)nrow * (F_ + H_) + k] = h;
        wg2l[(size_t)nrow * (F_ + H_) + k] = f2bf(v - bf2f(h));
    }
}

// attention scores + softmax: one block (512 thr) per batch element
__global__ __launch_bounds__(512) void attn_score(
    const float* __restrict__ h, const float* __restrict__ W_hidp,
    const float* __restrict__ b_hidp, const ush* __restrict__ fpb,
    const float* __restrict__ W_score, const float* __restrict__ b_score,
    float* __restrict__ alpha, float* __restrict__ alph_out, int t)
{
    __shared__ float sh_h[H_];
    __shared__ float sh_hp[A_];
    __shared__ float sh_ws[A_];
    __shared__ float sh_sc[200];
    __shared__ float red[2];
    const int tid = threadIdx.x;
    const int b = blockIdx.x;

    sh_h[tid] = h[b * H_ + tid];
    sh_ws[tid] = W_score[tid];
    __syncthreads();

    {
        const int a = tid;
        const float4* wr = reinterpret_cast<const float4*>(W_hidp + (size_t)a * H_);
        float acc = 0.f;
        #pragma unroll 8
        for (int kk = 0; kk < H_ / 4; ++kk) {
            const float4 w4 = wr[kk];
            acc += w4.x * sh_h[kk * 4 + 0] + w4.y * sh_h[kk * 4 + 1]
                 + w4.z * sh_h[kk * 4 + 2] + w4.w * sh_h[kk * 4 + 3];
        }
        sh_hp[a] = acc + b_hidp[a];
    }
    __syncthreads();

    const int lane = tid & 63, wid = tid >> 6;   // 8 waves
    for (int r = wid; r < R_; r += 8) {
        const ushort2* row = reinterpret_cast<const ushort2*>(fpb + ((size_t)b * R_ + r) * A_);
        float acc = 0.f;
        #pragma unroll
        for (int j = 0; j < 4; ++j) {
            const ushort2 u = row[lane + 64 * j];
            const int a = 2 * (lane + 64 * j);
            acc += fast_tanh(bf2f(u.x) + sh_hp[a]) * sh_ws[a];
            acc += fast_tanh(bf2f(u.y) + sh_hp[a + 1]) * sh_ws[a + 1];
        }
        for (int off = 32; off > 0; off >>= 1) acc += __shfl_down(acc, off);
        if (lane == 0) sh_sc[r] = acc + b_score[0];
    }
    __syncthreads();

    if (tid < 64) {
        float m = -1e30f;
        for (int r = tid; r < R_; r += 64) m = fmaxf(m, sh_sc[r]);
        for (int off = 32; off > 0; off >>= 1) m = fmaxf(m, __shfl_xor(m, off));
        float s = 0.f;
        for (int r = tid; r < R_; r += 64) s += __expf(sh_sc[r] - m);
        for (int off = 32; off > 0; off >>= 1) s += __shfl_xor(s, off);
        if (tid == 0) { red[0] = m; red[1] = 1.f / s; }
    }
    __syncthreads();
    const float m = red[0], is = red[1];
    if (tid < R_) {
        const float av = __expf(sh_sc[tid] - m) * is;
        alpha[b * R_ + tid] = av;
        alph_out[((size_t)b * L_ + t) * R_ + tid] = av;
    }
}

// context quarter: ctx[b, rs*512 + 2*tid + {0,1}] from fp32 feats
__global__ __launch_bounds__(256) void attn_context(
    const float* __restrict__ feats, const float* __restrict__ alpha,
    ush* __restrict__ ctx_hi, ush* __restrict__ ctx_lo)
{
    __shared__ float sa[R_];
    const int tid = threadIdx.x;
    const int rs = blockIdx.x;
    const int b = blockIdx.y;
    if (tid < R_) sa[tid] = alpha[b * R_ + tid];
    __syncthreads();

    const int f0 = rs * 512 + tid * 2;
    const float2* fp = reinterpret_cast<const float2*>(feats + (size_t)b * R_ * F_ + f0);
    float cx = 0.f, cy = 0.f;
    #pragma unroll 4
    for (int r = 0; r < R_; ++r) {
        const float a = sa[r];
        const float2 v = fp[(size_t)r * (F_ / 2)];
        cx = fmaf(a, v.x, cx); cy = fmaf(a, v.y, cy);
    }
    const size_t ci = (size_t)b * F_ + f0;
    const ush hx = f2bf(cx);
    ctx_hi[ci] = hx; ctx_lo[ci] = f2bf(cx - bf2f(hx));
    const ush hy = f2bf(cy);
    ctx_hi[ci + 1] = hy; ctx_lo[ci + 1] = f2bf(cy - bf2f(hy));
}

// LSTM cell: reduce 8 split-K partials + egates + biases; update h,c;
// write bf16 h into current (h_hi/h_lo) and history (hall) buffers
__global__ __launch_bounds__(256) void cell_kernel(
    const float* __restrict__ gparts, const float* __restrict__ egates,
    const float* __restrict__ b_ih, const float* __restrict__ b_hh,
    float* __restrict__ h, float* __restrict__ c,
    ush* __restrict__ h_hi, ush* __restrict__ h_lo,
    ush* __restrict__ hall_hi, ush* __restrict__ hall_lo, int t)
{
    const int idx = blockIdx.x * 256 + threadIdx.x;   // B*H = 32768
    const int b = idx >> 9, n = idx & 511;
    const float* eg = egates + ((size_t)b * L_ + t) * 2048;
    float gi = b_ih[n] + b_hh[n] + eg[n];
    float gf = b_ih[n + 512] + b_hh[n + 512] + eg[n + 512];
    float gg = b_ih[n + 1024] + b_hh[n + 1024] + eg[n + 1024];
    float go = b_ih[n + 1536] + b_hh[n + 1536] + eg[n + 1536];
    #pragma unroll
    for (int z = 0; z < 8; ++z) {
        const float* gz = gparts + (size_t)z * B_ * 2048 + (size_t)b * 2048;
        gi += gz[n]; gf += gz[n + 512]; gg += gz[n + 1024]; go += gz[n + 1536];
    }
    const float cc = fast_sig(gf) * c[idx] + fast_sig(gi) * fast_tanh(gg);
    const float hh = fast_sig(go) * fast_tanh(cc);
    c[idx] = cc;
    h[idx] = hh;
    const ush hi = f2bf(hh);
    const ush lo = f2bf(hh - bf2f(hi));
    h_hi[idx] = hi;
    h_lo[idx] = lo;
    const size_t hidx = ((size_t)t * B_ + b) * H_ + n;
    hall_hi[hidx] = hi;
    hall_lo[hidx] = lo;
}

extern "C" void kernel_launch(void* const* d_in, const int* in_sizes, int n_in,
                              void* d_out, int out_size, void* d_ws, size_t ws_size,
                              hipStream_t stream)
{
    const float* feats    = (const float*)d_in[0];
    const int*   cap      = (const int*)  d_in[1];
    const float* emb      = (const float*)d_in[2];
    const float* W_init_h = (const float*)d_in[3];
    const float* b_init_h = (const float*)d_in[4];
    const float* W_init_c = (const float*)d_in[5];
    const float* b_init_c = (const float*)d_in[6];
    const float* W_ih     = (const float*)d_in[7];
    const float* b_ih     = (const float*)d_in[8];
    const float* W_hh     = (const float*)d_in[9];
    const float* b_hh     = (const float*)d_in[10];
    const float* W_featp  = (const float*)d_in[11];
    const float* b_featp  = (const float*)d_in[12];
    const float* W_hidp   = (const float*)d_in[13];
    const float* b_hidp   = (const float*)d_in[14];
    const float* W_score  = (const float*)d_in[15];
    const float* b_score  = (const float*)d_in[16];
    const float* W_out    = (const float*)d_in[17];
    const float* b_out    = (const float*)d_in[18];

    float* pred     = (float*)d_out;                          // (B,L,V)
    float* alph_out = pred + (size_t)B_ * L_ * V_;            // (B,L,R)

    char* p = (char*)d_ws;
    auto alloc = [&](size_t bytes) { char* q = p; p += (bytes + 255) & ~(size_t)255; return q; };

    ush*   fpb    = (ush*)  alloc((size_t)B_ * R_ * A_ * 2);
    ush*   eh     = (ush*)  alloc((size_t)B_ * L_ * E_ * 2);
    ush*   el     = (ush*)  alloc((size_t)B_ * L_ * E_ * 2);
    ush*   mh     = (ush*)  alloc((size_t)B_ * F_ * 2);
    ush*   ml     = (ush*)  alloc((size_t)B_ * F_ * 2);
    ush*   fbh    = (ush*)  alloc((size_t)B_ * R_ * F_ * 2);
    ush*   wfp_h  = (ush*)  alloc((size_t)A_ * F_ * 2);
    ush*   wihh   = (ush*)  alloc((size_t)H_ * F_ * 2);
    ush*   wihl   = (ush*)  alloc((size_t)H_ * F_ * 2);
    ush*   wich   = (ush*)  alloc((size_t)H_ * F_ * 2);
    ush*   wicl   = (ush*)  alloc((size_t)H_ * F_ * 2);
    ush*   wxh    = (ush*)  alloc((size_t)2048 * E_ * 2);
    ush*   wxl    = (ush*)  alloc((size_t)2048 * E_ * 2);
    ush*   wg2h   = (ush*)  alloc((size_t)2048 * (F_ + H_) * 2);
    ush*   wg2l   = (ush*)  alloc((size_t)2048 * (F_ + H_) * 2);
    ush*   woh    = (ush*)  alloc((size_t)V_ * H_ * 2);
    ush*   wol    = (ush*)  alloc((size_t)V_ * H_ * 2);
    float* egates = (float*)alloc((size_t)B_ * L_ * 2048 * 4);
    float* h      = (float*)alloc((size_t)B_ * H_ * 4);
    float* c      = (float*)alloc((size_t)B_ * H_ * 4);
    ush*   h_hi   = (ush*)  alloc((size_t)B_ * H_ * 2);
    ush*   h_lo   = (ush*)  alloc((size_t)B_ * H_ * 2);
    ush*   hallh  = (ush*)  alloc((size_t)L_ * B_ * H_ * 2);
    ush*   halll  = (ush*)  alloc((size_t)L_ * B_ * H_ * 2);
    ush*   ctx_hi = (ush*)  alloc((size_t)B_ * F_ * 2);
    ush*   ctx_lo = (ush*)  alloc((size_t)B_ * F_ * 2);
    float* alpha  = (float*)alloc((size_t)B_ * R_ * 4);
    float* gparts = (float*)alloc((size_t)8 * B_ * 2048 * 4);

    // ---- one-time prep ----
    mean_split<<<128, 256, 0, stream>>>(feats, mh, ml);
    gather_split<<<768, 256, 0, stream>>>(emb, cap, eh, el);
    split_kernel<<<2048, 256, 0, stream>>>(W_out, woh, wol, V_ * H_ / 4);
    split_kernel<<<512, 256, 0, stream>>>(W_init_h, wihh, wihl, H_ * F_ / 4);
    split_kernel<<<512, 256, 0, stream>>>(W_init_c, wich, wicl, H_ * F_ / 4);
    split_kernel<<<512, 256, 0, stream>>>(W_featp, wfp_h, nullptr, A_ * F_ / 4);
    split_kernel<<<2048, 256, 0, stream>>>(feats, fbh, nullptr, B_ * R_ * F_ / 4);
    prep_wih<<<2048, 256, 0, stream>>>(W_ih, W_hh, wxh, wxl, wg2h, wg2l);

    // h0/c0 (SPLIT=3): M=64, N=512, K=2048  -> grid(m=1, n=2)
    gemm_big<3, 0><<<dim3(1, 2), 256, 0, stream>>>(
        mh, ml, F_, wihh, wihl, F_, b_init_h, h, H_, H_, F_);
    gemm_big<3, 0><<<dim3(1, 2), 256, 0, stream>>>(
        mh, ml, F_, wich, wicl, F_, b_init_c, c, H_, H_, F_);
    split_kernel<<<32, 256, 0, stream>>>(h, h_hi, h_lo, B_ * H_ / 4);

    // feat_proj (SPLIT=1, bf16 out): M=12544, N=512, K=2048 -> grid(196, 2)
    gemm_big<1, 1><<<dim3(196, 2), 256, 0, stream>>>(
        fbh, nullptr, F_, wfp_h, nullptr, F_, b_featp, fpb, A_, A_, F_);

    // emb gate part for ALL steps (SPLIT=3): M=1536, N=2048, K=512 -> grid(24, 8)
    gemm_big<3, 0><<<dim3(24, 8), 256, 0, stream>>>(
        eh, el, E_, wxh, wxl, E_, nullptr, egates, 2048, 2048, E_);

    // ---- sequential decode ----
    for (int t = 0; t < L_; ++t) {
        attn_score<<<B_, 512, 0, stream>>>(
            h, W_hidp, b_hidp, fpb, W_score, b_score, alpha, alph_out, t);

        attn_context<<<dim3(4, B_), 256, 0, stream>>>(feats, alpha, ctx_hi, ctx_lo);

        // gates partials: [ctx | h] @ wg2^T, K=2560, split-K=8 (kChunk=320)
        gemm_gates<<<dim3(32, 1, 8), 256, 0, stream>>>(
            ctx_hi, ctx_lo, F_, F_,
            h_hi, h_lo, H_,
            wg2h, wg2l, F_ + H_,
            gparts, 4 * H_, (long)B_ * 4 * H_, (F_ + H_) / 8);

        cell_kernel<<<128, 256, 0, stream>>>(
            gparts, egates, b_ih, b_hh, h, c, h_hi, h_lo, hallh, halll, t);
    }

    // predictions for ALL steps (SPLIT=3): M=1536, N=12000, K=512 -> grid(24, 47)
    gemm_big<3, 2><<<dim3(24, 47), 256, 0, stream>>>(
        hallh, halll, H_, woh, wol, H_, b_out, pred, 0, V_, H_);
}

// Round 5
// 2587.319 us; speedup vs baseline: 1.4132x; 1.1745x over previous
//
#include <hip/hip_runtime.h>

#define B_ 64
#define R_ 196
#define F_ 2048
#define E_ 512
#define H_ 512
#define A_ 512
#define V_ 12000
#define L_ 24

typedef __attribute__((ext_vector_type(8))) short bf16x8;
typedef __attribute__((ext_vector_type(4))) float f32x4;
typedef unsigned short ush;

__device__ __forceinline__ float fast_tanh(float x) {
    float t = __expf(2.f * x);
    return 1.f - 2.f / (t + 1.f);
}
__device__ __forceinline__ float fast_sig(float x) {
    return 1.f / (1.f + __expf(-x));
}
__device__ __forceinline__ ush f2bf(float x) {
    unsigned int u = __float_as_uint(x);
    return (ush)((u + 0x7fffu + ((u >> 16) & 1u)) >> 16);
}
__device__ __forceinline__ float bf2f(ush b) {
    return __uint_as_float(((unsigned int)b) << 16);
}

#define LROW 40   // LDS row stride (32 k-elems + 8 pad)

// ---------------------------------------------------------------------------
// gemm_big: C[m,n] = A[m,:K] @ W[n,:K]^T (+bias). Tile 64M x 256N, BK=32,
// 256 threads (4 waves); wave w owns n-range [64w,64w+64): 4x4 16x16 frags.
// XCD-chunked bijective swizzle (requires gridDim.x*gridDim.y % 8 == 0,
// else identity): each XCD gets a contiguous chunk of work ids -> its W
// working set stays L2-resident.
// NFAST=false: work order m-fastest (W-chunk per XCD small; pred GEMM).
// NFAST=true : work order n-fastest (A-tile reused across n; feat_proj).
// SPLIT=3: (hi,lo) bf16x2 inputs, 3 MFMAs -> near-fp32. SPLIT=1: hi only.
// CMAP: 0 = fp32 C[m*ldc+n]; 1 = bf16 C[m*ldc+n];
//       2 = pred layout C[(m&63)*L*V + (m>>6)*V + n] (fp32, NT stores).
// Epilogue stages 16-row quarters through LDS -> full-line coalesced stores.
// ---------------------------------------------------------------------------
template<int SPLIT, int CMAP, bool NFAST>
__global__ __launch_bounds__(256) void gemm_big(
    const ush* __restrict__ Ah, const ush* __restrict__ Al, int lda,
    const ush* __restrict__ Wh, const ush* __restrict__ Wl, int ldw,
    const float* __restrict__ bias, void* __restrict__ Cv,
    int ldc, int N, int K)
{
    constexpr int SMEM_BYTES = (SPLIT == 3) ? 51200 : 25600;
    __shared__ __align__(16) char smem[SMEM_BYTES];
    ush* sAh = (ush*)smem;                    // 64  x LROW
    ush* sBh = (ush*)(smem + 5120);           // 256 x LROW
    ush* sAl = (ush*)(smem + 25600);
    ush* sBl = (ush*)(smem + 30720);
    float* cst = (float*)(smem + 5120);       // epilogue reuse (16KB <= 20KB)

    const int tid = threadIdx.x;
    const int lane = tid & 63, w = tid >> 6;

    // ---- XCD-chunked swizzle ----
    const int nbx = gridDim.x, nby = gridDim.y;
    const int nwg = nbx * nby;
    int lin = blockIdx.x + nbx * blockIdx.y;
    if ((nwg & 7) == 0) {
        const int q = nwg >> 3;
        lin = (lin & 7) * q + (lin >> 3);
    }
    int bx, by;
    if constexpr (NFAST) { by = lin % nby; bx = lin / nby; }
    else                 { bx = lin % nbx; by = lin / nbx; }
    const int mtile = bx * 64;
    const int ntile = by * 256;

    const int fr = lane & 15, kg = (lane >> 4) * 8;
    const int arow = tid >> 2, aq = (tid & 3) * 8;   // staging coords

    f32x4 acc[4][4];
    #pragma unroll
    for (int mf = 0; mf < 4; ++mf)
        #pragma unroll
        for (int nf = 0; nf < 4; ++nf) acc[mf][nf] = {0.f, 0.f, 0.f, 0.f};

    const uint4 zv = make_uint4(0u, 0u, 0u, 0u);

    for (int kb = 0; kb < K; kb += 32) {
        uint4 a_h = *(const uint4*)(Ah + (size_t)(mtile + arow) * lda + kb + aq);
        uint4 a_l;
        uint4 b_h[4], b_l[4];
        #pragma unroll
        for (int p = 0; p < 4; ++p) {
            const int row = ntile + arow + 64 * p;
            b_h[p] = (row < N) ? *(const uint4*)(Wh + (size_t)row * ldw + kb + aq) : zv;
        }
        if constexpr (SPLIT == 3) {
            a_l = *(const uint4*)(Al + (size_t)(mtile + arow) * lda + kb + aq);
            #pragma unroll
            for (int p = 0; p < 4; ++p) {
                const int row = ntile + arow + 64 * p;
                b_l[p] = (row < N) ? *(const uint4*)(Wl + (size_t)row * ldw + kb + aq) : zv;
            }
        }

        __syncthreads();
        *(uint4*)(sAh + arow * LROW + aq) = a_h;
        #pragma unroll
        for (int p = 0; p < 4; ++p)
            *(uint4*)(sBh + (arow + 64 * p) * LROW + aq) = b_h[p];
        if constexpr (SPLIT == 3) {
            *(uint4*)(sAl + arow * LROW + aq) = a_l;
            #pragma unroll
            for (int p = 0; p < 4; ++p)
                *(uint4*)(sBl + (arow + 64 * p) * LROW + aq) = b_l[p];
        }
        __syncthreads();

        bf16x8 bh[4], bl[4];
        #pragma unroll
        for (int nf = 0; nf < 4; ++nf) {
            bh[nf] = *(const bf16x8*)(sBh + (w * 64 + nf * 16 + fr) * LROW + kg);
            if constexpr (SPLIT == 3)
                bl[nf] = *(const bf16x8*)(sBl + (w * 64 + nf * 16 + fr) * LROW + kg);
        }
        #pragma unroll
        for (int mf = 0; mf < 4; ++mf) {
            const bf16x8 ah = *(const bf16x8*)(sAh + (mf * 16 + fr) * LROW + kg);
            if constexpr (SPLIT == 3) {
                const bf16x8 al = *(const bf16x8*)(sAl + (mf * 16 + fr) * LROW + kg);
                #pragma unroll
                for (int nf = 0; nf < 4; ++nf) {
                    acc[mf][nf] = __builtin_amdgcn_mfma_f32_16x16x32_bf16(ah, bh[nf], acc[mf][nf], 0, 0, 0);
                    acc[mf][nf] = __builtin_amdgcn_mfma_f32_16x16x32_bf16(ah, bl[nf], acc[mf][nf], 0, 0, 0);
                    acc[mf][nf] = __builtin_amdgcn_mfma_f32_16x16x32_bf16(al, bh[nf], acc[mf][nf], 0, 0, 0);
                }
            } else {
                #pragma unroll
                for (int nf = 0; nf < 4; ++nf)
                    acc[mf][nf] = __builtin_amdgcn_mfma_f32_16x16x32_bf16(ah, bh[nf], acc[mf][nf], 0, 0, 0);
            }
        }
    }

    // ---- LDS-staged epilogue: 4 quarters of 16 rows, full-line stores ----
    __syncthreads();
    const int nstore = ntile + tid;
    const bool sok = nstore < N;
    const float bv = (sok && bias) ? bias[nstore] : 0.f;
    const int colw = w * 64;
    #pragma unroll
    for (int mf = 0; mf < 4; ++mf) {
        #pragma unroll
        for (int nf = 0; nf < 4; ++nf) {
            const int col = colw + nf * 16 + fr;
            #pragma unroll
            for (int r = 0; r < 4; ++r)
                cst[((lane >> 4) * 4 + r) * 256 + col] = acc[mf][nf][r];
        }
        __syncthreads();
        if (sok) {
            #pragma unroll
            for (int rowq = 0; rowq < 16; ++rowq) {
                const int m = mtile + mf * 16 + rowq;
                const float v = cst[rowq * 256 + tid] + bv;
                if constexpr (CMAP == 1)
                    ((ush*)Cv)[(size_t)m * ldc + nstore] = f2bf(v);
                else if constexpr (CMAP == 2) {
                    float* dst = (float*)Cv + (size_t)(m & 63) * (L_ * V_)
                               + (size_t)(m >> 6) * V_ + nstore;
                    __builtin_nontemporal_store(v, dst);
                } else
                    ((float*)Cv)[(size_t)m * ldc + nstore] = v;
            }
        }
        __syncthreads();
    }
}

// ---------------------------------------------------------------------------
// gemm_gates: 64x64 tile, segmented A (2 segments), split-K via grid.z.
// Per-step gates GEMM: [ctx | h] @ [W_ih[:,E:] | W_hh]^T -> partials.
// ---------------------------------------------------------------------------
__global__ __launch_bounds__(256) void gemm_gates(
    const ush* __restrict__ Ah0, const ush* __restrict__ Al0, int lda0, int k0,
    const ush* __restrict__ Ah1, const ush* __restrict__ Al1, int lda1,
    const ush* __restrict__ Wh, const ush* __restrict__ Wl, int ldw,
    float* __restrict__ C, int ldc, long zstride, int kChunk)
{
    __shared__ ush sAh[64 * LROW];
    __shared__ ush sBh[64 * LROW];
    __shared__ ush sAl[64 * LROW];
    __shared__ ush sBl[64 * LROW];

    const int tid = threadIdx.x;
    const int ntile = blockIdx.x * 64;
    const int kStart = blockIdx.z * kChunk;
    const int lane = tid & 63, w = tid >> 6;
    const int lrow = tid >> 2;
    const int lcol = (tid & 3) * 8;
    const int nrow = ntile + lrow;

    f32x4 acc[4];
    #pragma unroll
    for (int f = 0; f < 4; ++f) acc[f] = {0.f, 0.f, 0.f, 0.f};

    const int fr = lane & 15;
    const int kg = (lane >> 4) * 8;

    for (int kb = kStart; kb < kStart + kChunk; kb += 32) {
        const ush *ph, *pl; int lda, loc;
        if (kb < k0) { ph = Ah0; pl = Al0; lda = lda0; loc = kb; }
        else         { ph = Ah1; pl = Al1; lda = lda1; loc = kb - k0; }

        uint4 a_h = *(const uint4*)(ph + (size_t)lrow * lda + loc + lcol);
        uint4 b_h = *(const uint4*)(Wh + (size_t)nrow * ldw + kb + lcol);
        uint4 a_l = *(const uint4*)(pl + (size_t)lrow * lda + loc + lcol);
        uint4 b_l = *(const uint4*)(Wl + (size_t)nrow * ldw + kb + lcol);

        __syncthreads();
        *(uint4*)(sAh + lrow * LROW + lcol) = a_h;
        *(uint4*)(sBh + lrow * LROW + lcol) = b_h;
        *(uint4*)(sAl + lrow * LROW + lcol) = a_l;
        *(uint4*)(sBl + lrow * LROW + lcol) = b_l;
        __syncthreads();

        const bf16x8 bh = *(const bf16x8*)(sBh + (16 * w + fr) * LROW + kg);
        const bf16x8 bl = *(const bf16x8*)(sBl + (16 * w + fr) * LROW + kg);

        #pragma unroll
        for (int f = 0; f < 4; ++f) {
            const bf16x8 ah = *(const bf16x8*)(sAh + (16 * f + fr) * LROW + kg);
            const bf16x8 al = *(const bf16x8*)(sAl + (16 * f + fr) * LROW + kg);
            acc[f] = __builtin_amdgcn_mfma_f32_16x16x32_bf16(ah, bh, acc[f], 0, 0, 0);
            acc[f] = __builtin_amdgcn_mfma_f32_16x16x32_bf16(ah, bl, acc[f], 0, 0, 0);
            acc[f] = __builtin_amdgcn_mfma_f32_16x16x32_bf16(al, bh, acc[f], 0, 0, 0);
        }
    }

    const int n = ntile + 16 * w + (lane & 15);
    float* Cz = C + (size_t)blockIdx.z * zstride;
    #pragma unroll
    for (int f = 0; f < 4; ++f)
        #pragma unroll
        for (int r = 0; r < 4; ++r) {
            const int m = 16 * f + (lane >> 4) * 4 + r;
            Cz[(size_t)m * ldc + n] = acc[f][r];
        }
}

// fused feats pass: fbh (bf16) + per-(b,f) mean -> mh/ml. block (fs, b).
__global__ __launch_bounds__(256) void prep_feats(
    const float* __restrict__ feats, ush* __restrict__ fbh,
    ush* __restrict__ mh, ush* __restrict__ ml)
{
    const int fs = blockIdx.x;          // 0..3
    const int b  = blockIdx.y;          // 0..63
    const int f = fs * 512 + threadIdx.x * 2;
    const float2* fp = (const float2*)(feats + (size_t)b * R_ * F_ + f);
    ush* fo = fbh + (size_t)b * R_ * F_ + f;
    float sx = 0.f, sy = 0.f;
    for (int r = 0; r < R_; ++r) {
        const float2 v = fp[(size_t)r * (F_ / 2)];
        sx += v.x; sy += v.y;
        ushort2 u; u.x = f2bf(v.x); u.y = f2bf(v.y);
        *(ushort2*)(fo + (size_t)r * F_) = u;
    }
    const float s = 1.f / (float)R_;
    sx *= s; sy *= s;
    const size_t mi = (size_t)b * F_ + f;
    const ush hx = f2bf(sx); mh[mi] = hx;     ml[mi] = f2bf(sx - bf2f(hx));
    const ush hy = f2bf(sy); mh[mi + 1] = hy; ml[mi + 1] = f2bf(sy - bf2f(hy));
}

// gather embeddings -> bf16 hi/lo (B,L,E)
__global__ __launch_bounds__(256) void gather_split(
    const float* __restrict__ emb, const int* __restrict__ cap,
    ush* __restrict__ eh, ush* __restrict__ el)
{
    const int idx = blockIdx.x * 256 + threadIdx.x;   // 196608
    const int bt = idx >> 7, j = idx & 127;
    const int tok = cap[bt];
    const float4 v = reinterpret_cast<const float4*>(emb)[(size_t)tok * (E_ / 4) + j];
    const float a[4] = {v.x, v.y, v.z, v.w};
    #pragma unroll
    for (int c = 0; c < 4; ++c) {
        const ush hi = f2bf(a[c]);
        eh[idx * 4 + c] = hi;
        el[idx * 4 + c] = f2bf(a[c] - bf2f(hi));
    }
}

// generic fp32 -> bf16 (hi, optional lo)
__global__ __launch_bounds__(256) void split_kernel(
    const float* __restrict__ in, ush* __restrict__ hi, ush* __restrict__ lo, int n4)
{
    for (int i = blockIdx.x * 256 + threadIdx.x; i < n4; i += gridDim.x * 256) {
        const float4 v = reinterpret_cast<const float4*>(in)[i];
        const float a[4] = {v.x, v.y, v.z, v.w};
        #pragma unroll
        for (int c = 0; c < 4; ++c) {
            const ush h = f2bf(a[c]);
            hi[i * 4 + c] = h;
            if (lo) lo[i * 4 + c] = f2bf(a[c] - bf2f(h));
        }
    }
}

// W_ih columns [0:E) -> wx (2048x512); [E:) ++ W_hh -> wg2 (2048x2560); hi/lo
__global__ __launch_bounds__(256) void prep_wih(
    const float* __restrict__ W_ih, const float* __restrict__ W_hh,
    ush* __restrict__ wxh, ush* __restrict__ wxl,
    ush* __restrict__ wg2h, ush* __restrict__ wg2l)
{
    const int nrow = blockIdx.x;   // 2048
    for (int k = threadIdx.x; k < E_; k += 256) {
        const float v = W_ih[(size_t)nrow * (E_ + F_) + k];
        const ush h = f2bf(v);
        wxh[(size_t)nrow * E_ + k] = h;
        wxl[(size_t)nrow * E_ + k] = f2bf(v - bf2f(h));
    }
    for (int k = threadIdx.x; k < F_ + H_; k += 256) {
        const float v = (k < F_) ? W_ih[(size_t)nrow * (E_ + F_) + E_ + k]
                                 : W_hh[(size_t)nrow * H_ + (k - F_)];
        const ush h = f2bf(v);
        wg2h[(size_t)nrow * (F_ + H_) + k] = h;
        wg2l[(size_t)nrow * (F_ + H_) + k] = f2bf(v - bf2f(h));
    }
}

// transpose W_hidp (A x H) -> whpT (H x A), fp32
__global__ __launch_bounds__(256) void transpose512(
    const float* __restrict__ in, float* __restrict__ out)
{
    const int idx = blockIdx.x * 256 + threadIdx.x;   // 262144
    const int k = idx >> 9, a = idx & 511;
    out[idx] = in[(size_t)a * 512 + k];
    (void)k;
}

// attention scores + softmax: one block (512 thr) per batch element.
// hid_proj uses TRANSPOSED W_hidp (coalesced).
__global__ __launch_bounds__(512) void attn_score(
    const float* __restrict__ h, const float* __restrict__ whpT,
    const float* __restrict__ b_hidp, const ush* __restrict__ fpb,
    const float* __restrict__ W_score, const float* __restrict__ b_score,
    float* __restrict__ alpha, float* __restrict__ alph_out, int t)
{
    __shared__ float sh_h[H_];
    __shared__ float sh_hp[A_];
    __shared__ float sh_ws[A_];
    __shared__ float sh_sc[200];
    __shared__ float red[2];
    const int tid = threadIdx.x;
    const int b = blockIdx.x;

    sh_h[tid] = h[b * H_ + tid];
    sh_ws[tid] = W_score[tid];
    __syncthreads();

    {
        float a0 = 0.f, a1 = 0.f, a2 = 0.f, a3 = 0.f;
        #pragma unroll 4
        for (int k = 0; k < H_; k += 4) {
            a0 = fmaf(sh_h[k + 0], whpT[(size_t)(k + 0) * A_ + tid], a0);
            a1 = fmaf(sh_h[k + 1], whpT[(size_t)(k + 1) * A_ + tid], a1);
            a2 = fmaf(sh_h[k + 2], whpT[(size_t)(k + 2) * A_ + tid], a2);
            a3 = fmaf(sh_h[k + 3], whpT[(size_t)(k + 3) * A_ + tid], a3);
        }
        sh_hp[tid] = (a0 + a1) + (a2 + a3) + b_hidp[tid];
    }
    __syncthreads();

    const int lane = tid & 63, wid = tid >> 6;   // 8 waves
    for (int r = wid; r < R_; r += 8) {
        const ushort2* row = reinterpret_cast<const ushort2*>(fpb + ((size_t)b * R_ + r) * A_);
        float acc = 0.f;
        #pragma unroll
        for (int j = 0; j < 4; ++j) {
            const ushort2 u = row[lane + 64 * j];
            const int a = 2 * (lane + 64 * j);
            acc += fast_tanh(bf2f(u.x) + sh_hp[a]) * sh_ws[a];
            acc += fast_tanh(bf2f(u.y) + sh_hp[a + 1]) * sh_ws[a + 1];
        }
        for (int off = 32; off > 0; off >>= 1) acc += __shfl_down(acc, off);
        if (lane == 0) sh_sc[r] = acc + b_score[0];
    }
    __syncthreads();

    if (tid < 64) {
        float m = -1e30f;
        for (int r = tid; r < R_; r += 64) m = fmaxf(m, sh_sc[r]);
        for (int off = 32; off > 0; off >>= 1) m = fmaxf(m, __shfl_xor(m, off));
        float s = 0.f;
        for (int r = tid; r < R_; r += 64) s += __expf(sh_sc[r] - m);
        for (int off = 32; off > 0; off >>= 1) s += __shfl_xor(s, off);
        if (tid == 0) { red[0] = m; red[1] = 1.f / s; }
    }
    __syncthreads();
    const float m = red[0], is = red[1];
    if (tid < R_) {
        const float av = __expf(sh_sc[tid] - m) * is;
        alpha[b * R_ + tid] = av;
        alph_out[((size_t)b * L_ + t) * R_ + tid] = av;
    }
}

// context quarter from bf16 feats: ctx[b, rs*512 + 2*tid + {0,1}]
__global__ __launch_bounds__(256) void attn_context(
    const ush* __restrict__ fbh, const float* __restrict__ alpha,
    ush* __restrict__ ctx_hi, ush* __restrict__ ctx_lo)
{
    __shared__ float sa[R_];
    const int tid = threadIdx.x;
    const int rs = blockIdx.x;
    const int b = blockIdx.y;
    if (tid < R_) sa[tid] = alpha[b * R_ + tid];
    __syncthreads();

    const int f0 = rs * 512 + tid * 2;
    const ush* fp = fbh + (size_t)b * R_ * F_ + f0;
    float cx = 0.f, cy = 0.f;
    #pragma unroll 4
    for (int r = 0; r < R_; ++r) {
        const float a = sa[r];
        const ushort2 u = *(const ushort2*)(fp + (size_t)r * F_);
        cx = fmaf(a, bf2f(u.x), cx); cy = fmaf(a, bf2f(u.y), cy);
    }
    const size_t ci = (size_t)b * F_ + f0;
    const ush hx = f2bf(cx);
    ctx_hi[ci] = hx; ctx_lo[ci] = f2bf(cx - bf2f(hx));
    const ush hy = f2bf(cy);
    ctx_hi[ci + 1] = hy; ctx_lo[ci + 1] = f2bf(cy - bf2f(hy));
}

// LSTM cell: reduce 8 split-K partials + egates + biases; update h,c;
// write bf16 h into current (h_hi/h_lo) and history (hall) buffers
__global__ __launch_bounds__(256) void cell_kernel(
    const float* __restrict__ gparts, const float* __restrict__ egates,
    const float* __restrict__ b_ih, const float* __restrict__ b_hh,
    float* __restrict__ h, float* __restrict__ c,
    ush* __restrict__ h_hi, ush* __restrict__ h_lo,
    ush* __restrict__ hall_hi, ush* __restrict__ hall_lo, int t)
{
    const int idx = blockIdx.x * 256 + threadIdx.x;   // B*H = 32768
    const int b = idx >> 9, n = idx & 511;
    const float* eg = egates + ((size_t)b * L_ + t) * 2048;
    float gi = b_ih[n] + b_hh[n] + eg[n];
    float gf = b_ih[n + 512] + b_hh[n + 512] + eg[n + 512];
    float gg = b_ih[n + 1024] + b_hh[n + 1024] + eg[n + 1024];
    float go = b_ih[n + 1536] + b_hh[n + 1536] + eg[n + 1536];
    #pragma unroll
    for (int z = 0; z < 8; ++z) {
        const float* gz = gparts + (size_t)z * B_ * 2048 + (size_t)b * 2048;
        gi += gz[n]; gf += gz[n + 512]; gg += gz[n + 1024]; go += gz[n + 1536];
    }
    const float cc = fast_sig(gf) * c[idx] + fast_sig(gi) * fast_tanh(gg);
    const float hh = fast_sig(go) * fast_tanh(cc);
    c[idx] = cc;
    h[idx] = hh;
    const ush hi = f2bf(hh);
    const ush lo = f2bf(hh - bf2f(hi));
    h_hi[idx] = hi;
    h_lo[idx] = lo;
    const size_t hidx = ((size_t)t * B_ + b) * H_ + n;
    hall_hi[hidx] = hi;
    hall_lo[hidx] = lo;
}

extern "C" void kernel_launch(void* const* d_in, const int* in_sizes, int n_in,
                              void* d_out, int out_size, void* d_ws, size_t ws_size,
                              hipStream_t stream)
{
    const float* feats    = (const float*)d_in[0];
    const int*   cap      = (const int*)  d_in[1];
    const float* emb      = (const float*)d_in[2];
    const float* W_init_h = (const float*)d_in[3];
    const float* b_init_h = (const float*)d_in[4];
    const float* W_init_c = (const float*)d_in[5];
    const float* b_init_c = (const float*)d_in[6];
    const float* W_ih     = (const float*)d_in[7];
    const float* b_ih     = (const float*)d_in[8];
    const float* W_hh     = (const float*)d_in[9];
    const float* b_hh     = (const float*)d_in[10];
    const float* W_featp  = (const float*)d_in[11];
    const float* b_featp  = (const float*)d_in[12];
    const float* W_hidp   = (const float*)d_in[13];
    const float* b_hidp   = (const float*)d_in[14];
    const float* W_score  = (const float*)d_in[15];
    const float* b_score  = (const float*)d_in[16];
    const float* W_out    = (const float*)d_in[17];
    const float* b_out    = (const float*)d_in[18];

    float* pred     = (float*)d_out;                          // (B,L,V)
    float* alph_out = pred + (size_t)B_ * L_ * V_;            // (B,L,R)

    char* p = (char*)d_ws;
    auto alloc = [&](size_t bytes) { char* q = p; p += (bytes + 255) & ~(size_t)255; return q; };

    ush*   fpb    = (ush*)  alloc((size_t)B_ * R_ * A_ * 2);
    ush*   eh     = (ush*)  alloc((size_t)B_ * L_ * E_ * 2);
    ush*   el     = (ush*)  alloc((size_t)B_ * L_ * E_ * 2);
    ush*   mh     = (ush*)  alloc((size_t)B_ * F_ * 2);
    ush*   ml     = (ush*)  alloc((size_t)B_ * F_ * 2);
    ush*   fbh    = (ush*)  alloc((size_t)B_ * R_ * F_ * 2);
    ush*   wfp_h  = (ush*)  alloc((size_t)A_ * F_ * 2);
    ush*   wihh   = (ush*)  alloc((size_t)H_ * F_ * 2);
    ush*   wihl   = (ush*)  alloc((size_t)H_ * F_ * 2);
    ush*   wich   = (ush*)  alloc((size_t)H_ * F_ * 2);
    ush*   wicl   = (ush*)  alloc((size_t)H_ * F_ * 2);
    ush*   wxh    = (ush*)  alloc((size_t)2048 * E_ * 2);
    ush*   wxl    = (ush*)  alloc((size_t)2048 * E_ * 2);
    ush*   wg2h   = (ush*)  alloc((size_t)2048 * (F_ + H_) * 2);
    ush*   wg2l   = (ush*)  alloc((size_t)2048 * (F_ + H_) * 2);
    ush*   woh    = (ush*)  alloc((size_t)V_ * H_ * 2);
    ush*   wol    = (ush*)  alloc((size_t)V_ * H_ * 2);
    float* whpT   = (float*)alloc((size_t)H_ * A_ * 4);
    float* egates = (float*)alloc((size_t)B_ * L_ * 2048 * 4);
    float* h      = (float*)alloc((size_t)B_ * H_ * 4);
    float* c      = (float*)alloc((size_t)B_ * H_ * 4);
    ush*   h_hi   = (ush*)  alloc((size_t)B_ * H_ * 2);
    ush*   h_lo   = (ush*)  alloc((size_t)B_ * H_ * 2);
    ush*   hallh  = (ush*)  alloc((size_t)L_ * B_ * H_ * 2);
    ush*   halll  = (ush*)  alloc((size_t)L_ * B_ * H_ * 2);
    ush*   ctx_hi = (ush*)  alloc((size_t)B_ * F_ * 2);
    ush*   ctx_lo = (ush*)  alloc((size_t)B_ * F_ * 2);
    float* alpha  = (float*)alloc((size_t)B_ * R_ * 4);
    float* gparts = (float*)alloc((size_t)8 * B_ * 2048 * 4);

    // ---- one-time prep ----
    prep_feats<<<dim3(4, B_), 256, 0, stream>>>(feats, fbh, mh, ml);
    gather_split<<<768, 256, 0, stream>>>(emb, cap, eh, el);
    split_kernel<<<2048, 256, 0, stream>>>(W_out, woh, wol, V_ * H_ / 4);
    split_kernel<<<512, 256, 0, stream>>>(W_init_h, wihh, wihl, H_ * F_ / 4);
    split_kernel<<<512, 256, 0, stream>>>(W_init_c, wich, wicl, H_ * F_ / 4);
    split_kernel<<<512, 256, 0, stream>>>(W_featp, wfp_h, nullptr, A_ * F_ / 4);
    prep_wih<<<2048, 256, 0, stream>>>(W_ih, W_hh, wxh, wxl, wg2h, wg2l);
    transpose512<<<1024, 256, 0, stream>>>(W_hidp, whpT);

    // h0/c0 (SPLIT=3): M=64, N=512, K=2048  -> grid(1,2), nwg=2 (no swizzle)
    gemm_big<3, 0, false><<<dim3(1, 2), 256, 0, stream>>>(
        mh, ml, F_, wihh, wihl, F_, b_init_h, h, H_, H_, F_);
    gemm_big<3, 0, false><<<dim3(1, 2), 256, 0, stream>>>(
        mh, ml, F_, wich, wicl, F_, b_init_c, c, H_, H_, F_);
    split_kernel<<<32, 256, 0, stream>>>(h, h_hi, h_lo, B_ * H_ / 4);

    // feat_proj (SPLIT=1, bf16 out): M=12544, N=512 -> grid(196,2), NFAST
    gemm_big<1, 1, true><<<dim3(196, 2), 256, 0, stream>>>(
        fbh, nullptr, F_, wfp_h, nullptr, F_, b_featp, fpb, A_, A_, F_);

    // emb gate part for ALL steps (SPLIT=3): M=1536, N=2048 -> grid(24,8)
    gemm_big<3, 0, false><<<dim3(24, 8), 256, 0, stream>>>(
        eh, el, E_, wxh, wxl, E_, nullptr, egates, 2048, 2048, E_);

    // ---- sequential decode ----
    for (int t = 0; t < L_; ++t) {
        attn_score<<<B_, 512, 0, stream>>>(
            h, whpT, b_hidp, fpb, W_score, b_score, alpha, alph_out, t);

        attn_context<<<dim3(4, B_), 256, 0, stream>>>(fbh, alpha, ctx_hi, ctx_lo);

        // gates partials: [ctx | h] @ wg2^T, K=2560, split-K=8 (kChunk=320)
        gemm_gates<<<dim3(32, 1, 8), 256, 0, stream>>>(
            ctx_hi, ctx_lo, F_, F_,
            h_hi, h_lo, H_,
            wg2h, wg2l, F_ + H_,
            gparts, 4 * H_, (long)B_ * 4 * H_, (F_ + H_) / 8);

        cell_kernel<<<128, 256, 0, stream>>>(
            gparts, egates, b_ih, b_hh, h, c, h_hi, h_lo, hallh, halll, t);
    }

    // predictions for ALL steps (SPLIT=3): M=1536, N=12000 -> grid(24,47)
    gemm_big<3, 2, false><<<dim3(24, 47), 256, 0, stream>>>(
        hallh, halll, H_, woh, wol, H_, b_out, pred, 0, V_, H_);
}

// Round 6
// 1974.049 us; speedup vs baseline: 1.8523x; 1.3107x over previous
//
#include <hip/hip_runtime.h>

#define B_ 64
#define R_ 196
#define F_ 2048
#define E_ 512
#define H_ 512
#define A_ 512
#define V_ 12000
#define L_ 24

typedef __attribute__((ext_vector_type(8))) short bf16x8;
typedef __attribute__((ext_vector_type(8))) unsigned short ushort8_t;
typedef __attribute__((ext_vector_type(4))) float f32x4;
typedef unsigned short ush;

__device__ __forceinline__ float fast_tanh(float x) {
    float t = __expf(2.f * x);
    return 1.f - 2.f / (t + 1.f);
}
__device__ __forceinline__ float fast_sig(float x) {
    return 1.f / (1.f + __expf(-x));
}
__device__ __forceinline__ ush f2bf(float x) {
    unsigned int u = __float_as_uint(x);
    return (ush)((u + 0x7fffu + ((u >> 16) & 1u)) >> 16);
}
__device__ __forceinline__ float bf2f(ush b) {
    return __uint_as_float(((unsigned int)b) << 16);
}

#define LROW 40   // LDS row stride (32 k-elems + 8 pad)

// ---------------------------------------------------------------------------
// gemm_big: C[m,n] = A[m,:K] @ W[n,:K]^T (+bias). Tile 64M x 256N, BK=32,
// 256 threads (4 waves); wave w owns n-range [64w,64w+64): 4x4 16x16 frags.
// XCD-chunked bijective swizzle (nwg%8==0 else identity). NFAST: n-fastest
// work order (A reuse); else m-fastest (W-chunk per XCD stays L2-resident).
// SPLIT=3: (hi,lo) bf16x2 inputs, 3 MFMAs -> near-fp32. SPLIT=1: hi only.
// CMAP: 0 = fp32 C[m*ldc+n]; 1 = bf16 C[m*ldc+n];
//       2 = pred layout C[(m&63)*L*V + (m>>6)*V + n] (fp32, NT stores).
// Direct-store epilogue: each 16-lane group writes one 64B line per reg.
// ---------------------------------------------------------------------------
template<int SPLIT, int CMAP, bool NFAST>
__global__ __launch_bounds__(256) void gemm_big(
    const ush* __restrict__ Ah, const ush* __restrict__ Al, int lda,
    const ush* __restrict__ Wh, const ush* __restrict__ Wl, int ldw,
    const float* __restrict__ bias, void* __restrict__ Cv,
    int ldc, int N, int K)
{
    constexpr int SMEM_BYTES = (SPLIT == 3) ? 51200 : 25600;
    __shared__ __align__(16) char smem[SMEM_BYTES];
    ush* sAh = (ush*)smem;                    // 64  x LROW
    ush* sBh = (ush*)(smem + 5120);           // 256 x LROW
    ush* sAl = (ush*)(smem + 25600);
    ush* sBl = (ush*)(smem + 30720);

    const int tid = threadIdx.x;
    const int lane = tid & 63, w = tid >> 6;

    // ---- XCD-chunked swizzle ----
    const int nbx = gridDim.x, nby = gridDim.y;
    const int nwg = nbx * nby;
    int lin = blockIdx.x + nbx * blockIdx.y;
    if ((nwg & 7) == 0) {
        const int q = nwg >> 3;
        lin = (lin & 7) * q + (lin >> 3);
    }
    int bx, by;
    if constexpr (NFAST) { by = lin % nby; bx = lin / nby; }
    else                 { bx = lin % nbx; by = lin / nbx; }
    const int mtile = bx * 64;
    const int ntile = by * 256;

    const int fr = lane & 15, kg = (lane >> 4) * 8;
    const int arow = tid >> 2, aq = (tid & 3) * 8;   // staging coords

    f32x4 acc[4][4];
    #pragma unroll
    for (int mf = 0; mf < 4; ++mf)
        #pragma unroll
        for (int nf = 0; nf < 4; ++nf) acc[mf][nf] = {0.f, 0.f, 0.f, 0.f};

    const uint4 zv = make_uint4(0u, 0u, 0u, 0u);

    for (int kb = 0; kb < K; kb += 32) {
        uint4 a_h = *(const uint4*)(Ah + (size_t)(mtile + arow) * lda + kb + aq);
        uint4 a_l;
        uint4 b_h[4], b_l[4];
        #pragma unroll
        for (int p = 0; p < 4; ++p) {
            const int row = ntile + arow + 64 * p;
            b_h[p] = (row < N) ? *(const uint4*)(Wh + (size_t)row * ldw + kb + aq) : zv;
        }
        if constexpr (SPLIT == 3) {
            a_l = *(const uint4*)(Al + (size_t)(mtile + arow) * lda + kb + aq);
            #pragma unroll
            for (int p = 0; p < 4; ++p) {
                const int row = ntile + arow + 64 * p;
                b_l[p] = (row < N) ? *(const uint4*)(Wl + (size_t)row * ldw + kb + aq) : zv;
            }
        }

        __syncthreads();
        *(uint4*)(sAh + arow * LROW + aq) = a_h;
        #pragma unroll
        for (int p = 0; p < 4; ++p)
            *(uint4*)(sBh + (arow + 64 * p) * LROW + aq) = b_h[p];
        if constexpr (SPLIT == 3) {
            *(uint4*)(sAl + arow * LROW + aq) = a_l;
            #pragma unroll
            for (int p = 0; p < 4; ++p)
                *(uint4*)(sBl + (arow + 64 * p) * LROW + aq) = b_l[p];
        }
        __syncthreads();

        bf16x8 bh[4], bl[4];
        #pragma unroll
        for (int nf = 0; nf < 4; ++nf) {
            bh[nf] = *(const bf16x8*)(sBh + (w * 64 + nf * 16 + fr) * LROW + kg);
            if constexpr (SPLIT == 3)
                bl[nf] = *(const bf16x8*)(sBl + (w * 64 + nf * 16 + fr) * LROW + kg);
        }
        #pragma unroll
        for (int mf = 0; mf < 4; ++mf) {
            const bf16x8 ah = *(const bf16x8*)(sAh + (mf * 16 + fr) * LROW + kg);
            if constexpr (SPLIT == 3) {
                const bf16x8 al = *(const bf16x8*)(sAl + (mf * 16 + fr) * LROW + kg);
                #pragma unroll
                for (int nf = 0; nf < 4; ++nf) {
                    acc[mf][nf] = __builtin_amdgcn_mfma_f32_16x16x32_bf16(ah, bh[nf], acc[mf][nf], 0, 0, 0);
                    acc[mf][nf] = __builtin_amdgcn_mfma_f32_16x16x32_bf16(ah, bl[nf], acc[mf][nf], 0, 0, 0);
                    acc[mf][nf] = __builtin_amdgcn_mfma_f32_16x16x32_bf16(al, bh[nf], acc[mf][nf], 0, 0, 0);
                }
            } else {
                #pragma unroll
                for (int nf = 0; nf < 4; ++nf)
                    acc[mf][nf] = __builtin_amdgcn_mfma_f32_16x16x32_bf16(ah, bh[nf], acc[mf][nf], 0, 0, 0);
            }
        }
    }

    // ---- direct-store epilogue ----
    #pragma unroll
    for (int nf = 0; nf < 4; ++nf) {
        const int nn = ntile + w * 64 + nf * 16 + fr;
        if (nn < N) {
            const float bv = bias ? bias[nn] : 0.f;
            #pragma unroll
            for (int mf = 0; mf < 4; ++mf) {
                #pragma unroll
                for (int r = 0; r < 4; ++r) {
                    const int m = mtile + mf * 16 + (lane >> 4) * 4 + r;
                    const float v = acc[mf][nf][r] + bv;
                    if constexpr (CMAP == 1)
                        ((ush*)Cv)[(size_t)m * ldc + nn] = f2bf(v);
                    else if constexpr (CMAP == 2) {
                        float* dst = (float*)Cv + (size_t)(m & 63) * (L_ * V_)
                                   + (size_t)(m >> 6) * V_ + nn;
                        __builtin_nontemporal_store(v, dst);
                    } else
                        ((float*)Cv)[(size_t)m * ldc + nn] = v;
                }
            }
        }
    }
}

// ---------------------------------------------------------------------------
// gemm_gates: 64x64 tile (M=64 rows), segmented A (2 segments), split-K via
// grid.z -> raw partials. Used for per-step gates AND the h0/c0 init GEMM.
// ---------------------------------------------------------------------------
__global__ __launch_bounds__(256) void gemm_gates(
    const ush* __restrict__ Ah0, const ush* __restrict__ Al0, int lda0, int k0,
    const ush* __restrict__ Ah1, const ush* __restrict__ Al1, int lda1,
    const ush* __restrict__ Wh, const ush* __restrict__ Wl, int ldw,
    float* __restrict__ C, int ldc, long zstride, int kChunk)
{
    __shared__ ush sAh[64 * LROW];
    __shared__ ush sBh[64 * LROW];
    __shared__ ush sAl[64 * LROW];
    __shared__ ush sBl[64 * LROW];

    const int tid = threadIdx.x;
    const int ntile = blockIdx.x * 64;
    const int kStart = blockIdx.z * kChunk;
    const int lane = tid & 63, w = tid >> 6;
    const int lrow = tid >> 2;
    const int lcol = (tid & 3) * 8;
    const int nrow = ntile + lrow;

    f32x4 acc[4];
    #pragma unroll
    for (int f = 0; f < 4; ++f) acc[f] = {0.f, 0.f, 0.f, 0.f};

    const int fr = lane & 15;
    const int kg = (lane >> 4) * 8;

    for (int kb = kStart; kb < kStart + kChunk; kb += 32) {
        const ush *ph, *pl; int lda, loc;
        if (kb < k0) { ph = Ah0; pl = Al0; lda = lda0; loc = kb; }
        else         { ph = Ah1; pl = Al1; lda = lda1; loc = kb - k0; }

        uint4 a_h = *(const uint4*)(ph + (size_t)lrow * lda + loc + lcol);
        uint4 b_h = *(const uint4*)(Wh + (size_t)nrow * ldw + kb + lcol);
        uint4 a_l = *(const uint4*)(pl + (size_t)lrow * lda + loc + lcol);
        uint4 b_l = *(const uint4*)(Wl + (size_t)nrow * ldw + kb + lcol);

        __syncthreads();
        *(uint4*)(sAh + lrow * LROW + lcol) = a_h;
        *(uint4*)(sBh + lrow * LROW + lcol) = b_h;
        *(uint4*)(sAl + lrow * LROW + lcol) = a_l;
        *(uint4*)(sBl + lrow * LROW + lcol) = b_l;
        __syncthreads();

        const bf16x8 bh = *(const bf16x8*)(sBh + (16 * w + fr) * LROW + kg);
        const bf16x8 bl = *(const bf16x8*)(sBl + (16 * w + fr) * LROW + kg);

        #pragma unroll
        for (int f = 0; f < 4; ++f) {
            const bf16x8 ah = *(const bf16x8*)(sAh + (16 * f + fr) * LROW + kg);
            const bf16x8 al = *(const bf16x8*)(sAl + (16 * f + fr) * LROW + kg);
            acc[f] = __builtin_amdgcn_mfma_f32_16x16x32_bf16(ah, bh, acc[f], 0, 0, 0);
            acc[f] = __builtin_amdgcn_mfma_f32_16x16x32_bf16(ah, bl, acc[f], 0, 0, 0);
            acc[f] = __builtin_amdgcn_mfma_f32_16x16x32_bf16(al, bh, acc[f], 0, 0, 0);
        }
    }

    const int n = ntile + 16 * w + (lane & 15);
    float* Cz = C + (size_t)blockIdx.z * zstride;
    #pragma unroll
    for (int f = 0; f < 4; ++f)
        #pragma unroll
        for (int r = 0; r < 4; ++r) {
            const int m = 16 * f + (lane >> 4) * 4 + r;
            Cz[(size_t)m * ldc + n] = acc[f][r];
        }
}

// fused feats pass: fbh (bf16) + per-(b,f) mean -> mh/ml. block (fs, b).
__global__ __launch_bounds__(256) void prep_feats(
    const float* __restrict__ feats, ush* __restrict__ fbh,
    ush* __restrict__ mh, ush* __restrict__ ml)
{
    const int fs = blockIdx.x;          // 0..3
    const int b  = blockIdx.y;          // 0..63
    const int f = fs * 512 + threadIdx.x * 2;
    const float2* fp = (const float2*)(feats + (size_t)b * R_ * F_ + f);
    ush* fo = fbh + (size_t)b * R_ * F_ + f;
    float sx = 0.f, sy = 0.f;
    for (int r = 0; r < R_; ++r) {
        const float2 v = fp[(size_t)r * (F_ / 2)];
        sx += v.x; sy += v.y;
        ushort2 u; u.x = f2bf(v.x); u.y = f2bf(v.y);
        *(ushort2*)(fo + (size_t)r * F_) = u;
    }
    const float s = 1.f / (float)R_;
    sx *= s; sy *= s;
    const size_t mi = (size_t)b * F_ + f;
    const ush hx = f2bf(sx); mh[mi] = hx;     ml[mi] = f2bf(sx - bf2f(hx));
    const ush hy = f2bf(sy); mh[mi + 1] = hy; ml[mi + 1] = f2bf(sy - bf2f(hy));
}

// gather embeddings -> bf16 hi/lo (B,L,E)
__global__ __launch_bounds__(256) void gather_split(
    const float* __restrict__ emb, const int* __restrict__ cap,
    ush* __restrict__ eh, ush* __restrict__ el)
{
    const int idx = blockIdx.x * 256 + threadIdx.x;   // 196608
    const int bt = idx >> 7, j = idx & 127;
    const int tok = cap[bt];
    const float4 v = reinterpret_cast<const float4*>(emb)[(size_t)tok * (E_ / 4) + j];
    const float a[4] = {v.x, v.y, v.z, v.w};
    #pragma unroll
    for (int c = 0; c < 4; ++c) {
        const ush hi = f2bf(a[c]);
        eh[idx * 4 + c] = hi;
        el[idx * 4 + c] = f2bf(a[c] - bf2f(hi));
    }
}

// generic fp32 -> bf16 (hi, optional lo)
__global__ __launch_bounds__(256) void split_kernel(
    const float* __restrict__ in, ush* __restrict__ hi, ush* __restrict__ lo, int n4)
{
    for (int i = blockIdx.x * 256 + threadIdx.x; i < n4; i += gridDim.x * 256) {
        const float4 v = reinterpret_cast<const float4*>(in)[i];
        const float a[4] = {v.x, v.y, v.z, v.w};
        #pragma unroll
        for (int c = 0; c < 4; ++c) {
            const ush h = f2bf(a[c]);
            hi[i * 4 + c] = h;
            if (lo) lo[i * 4 + c] = f2bf(a[c] - bf2f(h));
        }
    }
}

// W_ih columns [0:E) -> wx (2048x512); [E:) ++ W_hh -> wg2 (2048x2560); hi/lo
__global__ __launch_bounds__(256) void prep_wih(
    const float* __restrict__ W_ih, const float* __restrict__ W_hh,
    ush* __restrict__ wxh, ush* __restrict__ wxl,
    ush* __restrict__ wg2h, ush* __restrict__ wg2l)
{
    const int nrow = blockIdx.x;   // 2048
    for (int k = threadIdx.x; k < E_; k += 256) {
        const float v = W_ih[(size_t)nrow * (E_ + F_) + k];
        const ush h = f2bf(v);
        wxh[(size_t)nrow * E_ + k] = h;
        wxl[(size_t)nrow * E_ + k] = f2bf(v - bf2f(h));
    }
    for (int k = threadIdx.x; k < F_ + H_; k += 256) {
        const float v = (k < F_) ? W_ih[(size_t)nrow * (E_ + F_) + E_ + k]
                                 : W_hh[(size_t)nrow * H_ + (k - F_)];
        const ush h = f2bf(v);
        wg2h[(size_t)nrow * (F_ + H_) + k] = h;
        wg2l[(size_t)nrow * (F_ + H_) + k] = f2bf(v - bf2f(h));
    }
}

// transpose W_hidp (A x H) -> whpT (H x A), fp32
__global__ __launch_bounds__(256) void transpose512(
    const float* __restrict__ in, float* __restrict__ out)
{
    const int idx = blockIdx.x * 256 + threadIdx.x;   // 262144
    const int k = idx >> 9, a = idx & 511;
    out[idx] = in[(size_t)a * 512 + k];
    (void)k;
}

// reduce init GEMM partials: n<512 -> h0 (+split), n>=512 -> c0
__global__ __launch_bounds__(256) void init_reduce(
    const float* __restrict__ initp, const float* __restrict__ b_init_h,
    const float* __restrict__ b_init_c, float* __restrict__ h0f,
    float* __restrict__ c, ush* __restrict__ h_hi, ush* __restrict__ h_lo)
{
    const int idx = blockIdx.x * 256 + threadIdx.x;  // 65536
    const int b = idx >> 10, n = idx & 1023;
    float s = 0.f;
    #pragma unroll
    for (int z = 0; z < 8; ++z)
        s += initp[(size_t)z * (B_ * 1024) + (size_t)b * 1024 + n];
    if (n < 512) {
        s += b_init_h[n];
        h0f[b * H_ + n] = s;
        const ush hi = f2bf(s);
        h_hi[b * H_ + n] = hi;
        h_lo[b * H_ + n] = f2bf(s - bf2f(hi));
    } else {
        s += b_init_c[n - 512];
        c[b * H_ + (n - 512)] = s;
    }
}

// ---------------------------------------------------------------------------
// step_kernel<ATT>: per-b block, 512 threads.
// Phase A (t>0): LSTM cell for h_t from gparts(t-1)+egates(t-1); updates c,
//   h_hi/h_lo, hall[t-1]. (t==0: load h0.)
// Phase B..D (ATT): hid_proj -> scores(tanh over fpb) -> softmax -> alpha.
// ---------------------------------------------------------------------------
template<bool ATT>
__global__ __launch_bounds__(512) void step_kernel(
    const float* __restrict__ gparts, const float* __restrict__ egates,
    const float* __restrict__ b_ih, const float* __restrict__ b_hh,
    float* __restrict__ c, const float* __restrict__ h0f,
    ush* __restrict__ h_hi, ush* __restrict__ h_lo,
    ush* __restrict__ hall_hi, ush* __restrict__ hall_lo,
    const float* __restrict__ whpT, const float* __restrict__ b_hidp,
    const ush* __restrict__ fpb, const float* __restrict__ W_score,
    const float* __restrict__ b_score,
    float* __restrict__ alpha, float* __restrict__ alph_out, int t)
{
    __shared__ float sh_h[H_];
    __shared__ float sh_hp[A_];
    __shared__ float sh_ws[A_];
    __shared__ float sh_sc[200];
    __shared__ float red[2];
    const int tid = threadIdx.x;
    const int b = blockIdx.x;
    const int n = tid;

    float hh;
    if (t > 0) {
        const float* eg = egates + ((size_t)b * L_ + (t - 1)) * 2048;
        float gi = b_ih[n] + b_hh[n] + eg[n];
        float gf = b_ih[n + 512] + b_hh[n + 512] + eg[n + 512];
        float gg = b_ih[n + 1024] + b_hh[n + 1024] + eg[n + 1024];
        float go = b_ih[n + 1536] + b_hh[n + 1536] + eg[n + 1536];
        #pragma unroll
        for (int z = 0; z < 8; ++z) {
            const float* gz = gparts + (size_t)z * B_ * 2048 + (size_t)b * 2048;
            gi += gz[n]; gf += gz[n + 512]; gg += gz[n + 1024]; go += gz[n + 1536];
        }
        const float cc = fast_sig(gf) * c[b * H_ + n] + fast_sig(gi) * fast_tanh(gg);
        hh = fast_sig(go) * fast_tanh(cc);
        c[b * H_ + n] = cc;
        const ush hi = f2bf(hh);
        const ush lo = f2bf(hh - bf2f(hi));
        h_hi[b * H_ + n] = hi;
        h_lo[b * H_ + n] = lo;
        const size_t hidx = ((size_t)(t - 1) * B_ + b) * H_ + n;
        hall_hi[hidx] = hi;
        hall_lo[hidx] = lo;
    } else {
        hh = h0f[b * H_ + n];
    }
    if constexpr (!ATT) return;

    sh_h[n] = hh;
    sh_ws[n] = W_score[n];
    __syncthreads();

    // hid_proj (coalesced via transposed W_hidp)
    {
        float a0 = 0.f, a1 = 0.f, a2 = 0.f, a3 = 0.f;
        #pragma unroll 4
        for (int k = 0; k < H_; k += 4) {
            a0 = fmaf(sh_h[k + 0], whpT[(size_t)(k + 0) * A_ + tid], a0);
            a1 = fmaf(sh_h[k + 1], whpT[(size_t)(k + 1) * A_ + tid], a1);
            a2 = fmaf(sh_h[k + 2], whpT[(size_t)(k + 2) * A_ + tid], a2);
            a3 = fmaf(sh_h[k + 3], whpT[(size_t)(k + 3) * A_ + tid], a3);
        }
        sh_hp[tid] = (a0 + a1) + (a2 + a3) + b_hidp[tid];
    }
    __syncthreads();

    const int lane = tid & 63, wid = tid >> 6;   // 8 waves
    for (int r = wid; r < R_; r += 8) {
        const ushort2* row = reinterpret_cast<const ushort2*>(fpb + ((size_t)b * R_ + r) * A_);
        float acc = 0.f;
        #pragma unroll
        for (int j = 0; j < 4; ++j) {
            const ushort2 u = row[lane + 64 * j];
            const int a = 2 * (lane + 64 * j);
            acc += fast_tanh(bf2f(u.x) + sh_hp[a]) * sh_ws[a];
            acc += fast_tanh(bf2f(u.y) + sh_hp[a + 1]) * sh_ws[a + 1];
        }
        for (int off = 32; off > 0; off >>= 1) acc += __shfl_down(acc, off);
        if (lane == 0) sh_sc[r] = acc + b_score[0];
    }
    __syncthreads();

    if (tid < 64) {
        float m = -1e30f;
        for (int r = tid; r < R_; r += 64) m = fmaxf(m, sh_sc[r]);
        for (int off = 32; off > 0; off >>= 1) m = fmaxf(m, __shfl_xor(m, off));
        float s = 0.f;
        for (int r = tid; r < R_; r += 64) s += __expf(sh_sc[r] - m);
        for (int off = 32; off > 0; off >>= 1) s += __shfl_xor(s, off);
        if (tid == 0) { red[0] = m; red[1] = 1.f / s; }
    }
    __syncthreads();
    const float m = red[0], is = red[1];
    if (tid < R_) {
        const float av = __expf(sh_sc[tid] - m) * is;
        alpha[b * R_ + tid] = av;
        alph_out[((size_t)b * L_ + t) * R_ + tid] = av;
    }
}

// context partials: block (rs 0..6, b) sums 28 r-rows over all 2048 f
__global__ __launch_bounds__(256) void ctx_part(
    const ush* __restrict__ fbh, const float* __restrict__ alpha,
    float* __restrict__ ctxp)
{
    __shared__ float sa[28];
    const int rs = blockIdx.x;
    const int b  = blockIdx.y;
    const int tid = threadIdx.x;
    if (tid < 28) sa[tid] = alpha[b * R_ + rs * 28 + tid];
    __syncthreads();

    const int f0 = tid * 8;
    float acc[8] = {0.f, 0.f, 0.f, 0.f, 0.f, 0.f, 0.f, 0.f};
    const ush* base = fbh + ((size_t)b * R_ + rs * 28) * F_ + f0;
    #pragma unroll 4
    for (int i = 0; i < 28; ++i) {
        const ushort8_t u = *(const ushort8_t*)(base + (size_t)i * F_);
        const float a = sa[i];
        #pragma unroll
        for (int j = 0; j < 8; ++j) acc[j] = fmaf(a, bf2f(u[j]), acc[j]);
    }
    float* out = ctxp + ((size_t)(rs * B_ + b)) * F_ + f0;
    *(float4*)(out)     = make_float4(acc[0], acc[1], acc[2], acc[3]);
    *(float4*)(out + 4) = make_float4(acc[4], acc[5], acc[6], acc[7]);
}

// reduce 7 context partials -> ctx bf16 hi/lo
__global__ __launch_bounds__(256) void ctx_reduce(
    const float* __restrict__ ctxp, ush* __restrict__ ctx_hi, ush* __restrict__ ctx_lo)
{
    const int idx = blockIdx.x * 256 + threadIdx.x;   // 131072
    const int b = idx >> 11, f = idx & 2047;
    float s = 0.f;
    #pragma unroll
    for (int rs = 0; rs < 7; ++rs)
        s += ctxp[((size_t)(rs * B_ + b)) * F_ + f];
    const ush hi = f2bf(s);
    ctx_hi[(size_t)b * F_ + f] = hi;
    ctx_lo[(size_t)b * F_ + f] = f2bf(s - bf2f(hi));
}

extern "C" void kernel_launch(void* const* d_in, const int* in_sizes, int n_in,
                              void* d_out, int out_size, void* d_ws, size_t ws_size,
                              hipStream_t stream)
{
    const float* feats    = (const float*)d_in[0];
    const int*   cap      = (const int*)  d_in[1];
    const float* emb      = (const float*)d_in[2];
    const float* W_init_h = (const float*)d_in[3];
    const float* b_init_h = (const float*)d_in[4];
    const float* W_init_c = (const float*)d_in[5];
    const float* b_init_c = (const float*)d_in[6];
    const float* W_ih     = (const float*)d_in[7];
    const float* b_ih     = (const float*)d_in[8];
    const float* W_hh     = (const float*)d_in[9];
    const float* b_hh     = (const float*)d_in[10];
    const float* W_featp  = (const float*)d_in[11];
    const float* b_featp  = (const float*)d_in[12];
    const float* W_hidp   = (const float*)d_in[13];
    const float* b_hidp   = (const float*)d_in[14];
    const float* W_score  = (const float*)d_in[15];
    const float* b_score  = (const float*)d_in[16];
    const float* W_out    = (const float*)d_in[17];
    const float* b_out    = (const float*)d_in[18];

    float* pred     = (float*)d_out;                          // (B,L,V)
    float* alph_out = pred + (size_t)B_ * L_ * V_;            // (B,L,R)

    char* p = (char*)d_ws;
    auto alloc = [&](size_t bytes) { char* q = p; p += (bytes + 255) & ~(size_t)255; return q; };

    ush*   fpb    = (ush*)  alloc((size_t)B_ * R_ * A_ * 2);
    ush*   eh     = (ush*)  alloc((size_t)B_ * L_ * E_ * 2);
    ush*   el     = (ush*)  alloc((size_t)B_ * L_ * E_ * 2);
    ush*   mh     = (ush*)  alloc((size_t)B_ * F_ * 2);
    ush*   ml     = (ush*)  alloc((size_t)B_ * F_ * 2);
    ush*   fbh    = (ush*)  alloc((size_t)B_ * R_ * F_ * 2);
    ush*   wfp_h  = (ush*)  alloc((size_t)A_ * F_ * 2);
    ush*   wiH    = (ush*)  alloc((size_t)1024 * F_ * 2);     // [W_init_h; W_init_c] hi
    ush*   wiL    = (ush*)  alloc((size_t)1024 * F_ * 2);
    ush*   wxh    = (ush*)  alloc((size_t)2048 * E_ * 2);
    ush*   wxl    = (ush*)  alloc((size_t)2048 * E_ * 2);
    ush*   wg2h   = (ush*)  alloc((size_t)2048 * (F_ + H_) * 2);
    ush*   wg2l   = (ush*)  alloc((size_t)2048 * (F_ + H_) * 2);
    ush*   woh    = (ush*)  alloc((size_t)V_ * H_ * 2);
    ush*   wol    = (ush*)  alloc((size_t)V_ * H_ * 2);
    float* whpT   = (float*)alloc((size_t)H_ * A_ * 4);
    float* egates = (float*)alloc((size_t)B_ * L_ * 2048 * 4);
    float* h0f    = (float*)alloc((size_t)B_ * H_ * 4);
    float* c      = (float*)alloc((size_t)B_ * H_ * 4);
    ush*   h_hi   = (ush*)  alloc((size_t)B_ * H_ * 2);
    ush*   h_lo   = (ush*)  alloc((size_t)B_ * H_ * 2);
    ush*   hallh  = (ush*)  alloc((size_t)L_ * B_ * H_ * 2);
    ush*   halll  = (ush*)  alloc((size_t)L_ * B_ * H_ * 2);
    ush*   ctx_hi = (ush*)  alloc((size_t)B_ * F_ * 2);
    ush*   ctx_lo = (ush*)  alloc((size_t)B_ * F_ * 2);
    float* alpha  = (float*)alloc((size_t)B_ * R_ * 4);
    float* gparts = (float*)alloc((size_t)8 * B_ * 2048 * 4);
    float* initp  = (float*)alloc((size_t)8 * B_ * 1024 * 4);
    float* ctxp   = (float*)alloc((size_t)7 * B_ * F_ * 4);

    // ---- one-time prep ----
    prep_feats<<<dim3(4, B_), 256, 0, stream>>>(feats, fbh, mh, ml);
    gather_split<<<768, 256, 0, stream>>>(emb, cap, eh, el);
    split_kernel<<<2048, 256, 0, stream>>>(W_out, woh, wol, V_ * H_ / 4);
    split_kernel<<<512, 256, 0, stream>>>(W_init_h, wiH, wiL, H_ * F_ / 4);
    split_kernel<<<512, 256, 0, stream>>>(W_init_c, wiH + (size_t)512 * F_,
                                          wiL + (size_t)512 * F_, H_ * F_ / 4);
    split_kernel<<<512, 256, 0, stream>>>(W_featp, wfp_h, nullptr, A_ * F_ / 4);
    prep_wih<<<2048, 256, 0, stream>>>(W_ih, W_hh, wxh, wxl, wg2h, wg2l);
    transpose512<<<1024, 256, 0, stream>>>(W_hidp, whpT);

    // h0/c0 init: M=64, N=1024 (stacked), K=2048, split-K=8 -> 128 blocks
    gemm_gates<<<dim3(16, 1, 8), 256, 0, stream>>>(
        mh, ml, F_, F_,
        mh, ml, F_,
        wiH, wiL, F_,
        initp, 1024, (long)B_ * 1024, F_ / 8);
    init_reduce<<<256, 256, 0, stream>>>(initp, b_init_h, b_init_c, h0f, c, h_hi, h_lo);

    // feat_proj (SPLIT=1, bf16 out): M=12544, N=512 -> grid(196,2), NFAST
    gemm_big<1, 1, true><<<dim3(196, 2), 256, 0, stream>>>(
        fbh, nullptr, F_, wfp_h, nullptr, F_, b_featp, fpb, A_, A_, F_);

    // emb gate part for ALL steps (SPLIT=3): M=1536, N=2048 -> grid(24,8)
    gemm_big<3, 0, false><<<dim3(24, 8), 256, 0, stream>>>(
        eh, el, E_, wxh, wxl, E_, nullptr, egates, 2048, 2048, E_);

    // ---- sequential decode ----
    for (int t = 0; t < L_; ++t) {
        step_kernel<true><<<B_, 512, 0, stream>>>(
            gparts, egates, b_ih, b_hh, c, h0f, h_hi, h_lo, hallh, halll,
            whpT, b_hidp, fpb, W_score, b_score, alpha, alph_out, t);

        ctx_part<<<dim3(7, B_), 256, 0, stream>>>(fbh, alpha, ctxp);
        ctx_reduce<<<512, 256, 0, stream>>>(ctxp, ctx_hi, ctx_lo);

        // gates partials: [ctx | h] @ wg2^T, K=2560, split-K=8 (kChunk=320)
        gemm_gates<<<dim3(32, 1, 8), 256, 0, stream>>>(
            ctx_hi, ctx_lo, F_, F_,
            h_hi, h_lo, H_,
            wg2h, wg2l, F_ + H_,
            gparts, 4 * H_, (long)B_ * 4 * H_, (F_ + H_) / 8);
    }

    // final cell: h_L -> hall[L-1]
    step_kernel<false><<<B_, 512, 0, stream>>>(
        gparts, egates, b_ih, b_hh, c, h0f, h_hi, h_lo, hallh, halll,
        whpT, b_hidp, fpb, W_score, b_score, alpha, alph_out, L_);

    // predictions for ALL steps (SPLIT=3): M=1536, N=12000 -> grid(24,47)
    gemm_big<3, 2, false><<<dim3(24, 47), 256, 0, stream>>>(
        hallh, halll, H_, woh, wol, H_, b_out, pred, 0, V_, H_);
}